// Round 13
// baseline (231.539 us; speedup 1.0000x reference)
//
#include <hip/hip_runtime.h>

// ---------------------------------------------------------------------------
// Round 13 = Round 12 with the sbias LDS array removed.
//  - Biases are read directly from global ws at use sites (L2-hot,
//    address-static -> hoistable). LDS 28672 -> 26624 B: 6 blocks/CU by the
//    LDS formula (was 5). be/bf staging padded to 16 entries so the BEF use
//    site can read ws[STG_BE+mcol] for mcol<16.
// ---------------------------------------------------------------------------

#define IW 384
#define HW (384 * 384)           // 147456
#define NPIX (4 * HW)            // 589824
#define MTILE 128
#define NBLK (NPIX / MTILE)      // 4608
#define AST 52                   // acts row stride in dwords (48 data + 4 pad)

typedef _Float16 half8 __attribute__((ext_vector_type(8)));
typedef __fp16 fp16x2 __attribute__((ext_vector_type(2)));
typedef __attribute__((ext_vector_type(4))) float f32x4;
typedef __attribute__((ext_vector_type(4))) unsigned int uint4_;

#define MFMAH(A, B, C) __builtin_amdgcn_mfma_f32_16x16x32_f16((A), (B), (C), 0, 0, 0)

// bias table offsets (dwords in ws)
#define BA   0
#define B1   64
#define B2   144
#define BEF  224
#define BD   240
#define B4   304
#define B5   432
#define BOUT 496
#define BIAS_TOT 512

// weight image segment offsets (shorts, after bias table). frag = 512 shorts.
#define W_A0   0
#define W_A1   2048
#define W_A2   4096
#define W_H1A  6144
#define W_H1B  8704
#define W_H2A  11264
#define W_H2B  13824
#define W_H2C  16384
#define W_EF   18944    // E: 6 frags hi/lo (kt-major), F: 4 frags at +3072
#define W_D    24064    // 8 frags hi/lo (nt-major)
#define W_H4C0 28160    // chunk c: h4 at 28160+c*4096
#define W_H5C0 30208    //          h5 at 30208+c*4096
#define W_OUT  44544
#define W_TOT  45568

// be / bf slots (dword offsets, after images): 16 entries each, zero-padded
#define STG_BE  23296
#define STG_BF  23312

__device__ __forceinline__ float lrelu(float v) { return v >= 0.0f ? v : 0.01f * v; }

__device__ __forceinline__ float tanh_fast(float v) {
    float e = __expf(2.0f * v);
    return 1.0f - 2.0f * __builtin_amdgcn_rcpf(e + 1.0f);
}

__device__ __forceinline__ unsigned short f2h_bits(float v) {
    union { _Float16 h; unsigned short s; } u; u.h = (_Float16)v; return u.s;
}
__device__ __forceinline__ float h2f_bits(unsigned short s) {
    union { _Float16 h; unsigned short s; } u; u.s = s; return (float)u.h;
}
__device__ __forceinline__ unsigned packh2(float a, float b) {
    union { fp16x2 h; unsigned u; } u;
    u.h = __builtin_amdgcn_cvt_pkrtz(a, b);
    return u.u;
}

// deep-pipelined global->LDS staging: float4 x unroll-4
__device__ __forceinline__ void stage(float* dst, const float* __restrict__ src,
                                      int n, int tid) {
    int n4 = n >> 2;
    float4* d = (float4*)dst;
    const float4* s = (const float4*)src;
#pragma unroll 4
    for (int i = tid; i < n4; i += 256) d[i] = s[i];
    for (int i = (n4 << 2) + tid; i < n; i += 256) dst[i] = src[i];
}

// ---------------------------------------------------------------------------
// setup_all: 75 independent blocks x 256 threads.
// ---------------------------------------------------------------------------
__global__ __launch_bounds__(256) void setup_all(
    const float* __restrict__ W_input, const float* __restrict__ b_input,
    const float* __restrict__ W_h1,  const float* __restrict__ b_h1,
    const float* __restrict__ W_h2,  const float* __restrict__ b_h2,
    const float* __restrict__ W_h3,  const float* __restrict__ b_h3,
    const float* __restrict__ W_h4,  const float* __restrict__ b_h4,
    const float* __restrict__ W_h5,  const float* __restrict__ b_h5,
    const float* __restrict__ W_out, const float* __restrict__ b_out,
    const float* __restrict__ W_e1,  const float* __restrict__ b_e1,
    const float* __restrict__ W_e2,  const float* __restrict__ b_e2,
    const float* __restrict__ W_e3,  const float* __restrict__ b_e3,
    const float* __restrict__ W_f1,  const float* __restrict__ b_f1,
    const float* __restrict__ W_f2,  const float* __restrict__ b_f2,
    const float* __restrict__ W_f3,  const float* __restrict__ b_f3,
    const float* __restrict__ W_d1,  const float* __restrict__ b_d1,
    const float* __restrict__ W_d2,  const float* __restrict__ b_d2,
    const float* __restrict__ W_d3,  const float* __restrict__ b_d3,
    float* __restrict__ ws)
{
    const int tid = threadIdx.x;
    const int NT = 256;
    short* wimg = (short*)(ws + BIAS_TOT);

    if (blockIdx.x < 71) {
        const int soff[17] = {W_A0,W_A1,W_A2, W_H1A,W_H1B, W_H2A,W_H2B,W_H2C,
                              W_H4C0,W_H5C0, W_H4C0+4096,W_H5C0+4096,
                              W_H4C0+8192,W_H5C0+8192, W_H4C0+12288,W_H5C0+12288,
                              W_OUT};
        const int slay[17] = {0,0,0, 1,1, 2,2,2, 6,7, 6,7, 6,7, 6,7, 8};
        const int sNT[17]  = {4,4,4, 5,5, 5,5,5, 2,4, 2,4, 2,4, 2,4, 1};
        const int sKTS[17] = {1,1,1, 1,1, 1,1,1, 2,1, 2,1, 2,1, 2,1, 2};
        const int snb[17]  = {0,0,0, 0,0, 0,0,0, 0,0, 32,0, 64,0, 96,0, 0};
        const int skb[17]  = {0,32,64, 0,32, 0,32,64, 0,0, 0,32, 0,64, 0,96, 0};

        int seg = 0, local = blockIdx.x;
        while (seg < 16 && local >= sNT[seg] * sKTS[seg]) { local -= sNT[seg] * sKTS[seg]; seg++; }
        const int kts = sKTS[seg];
        const int kt = local % kts, nt = local / kts;
        const int lay = slay[seg];
        short* dst = wimg + soff[seg] + local * 512;

#pragma unroll
        for (int t = 0; t < 2; t++) {
            int idx = tid + t * 256;
            int j = idx & 7, lane = idx >> 3;
            int n = snb[seg] + nt * 16 + (lane & 15);
            int k = skb[seg] + kt * 32 + (lane >> 4) * 8 + j;
            float v = 0.0f;
            switch (lay) {
                case 0: if (n < 50  && k < 75)  v = W_input[n * 75 + k]; break;
                case 1: if (n < 75  && k < 50)  v = W_h1[n * 50 + k]; break;
                case 2: if (n < 75  && k < 75)  v = W_h2[n * 75 + k]; break;
                case 6: if (n < 125 && k < 50)  v = W_h4[n * 50 + k]; break;
                case 7: if (n < 50  && k < 125) v = W_h5[n * 125 + k]; break;
                case 8: if (n < 3   && k < 50)  v = W_out[n * 50 + k]; break;
            }
            dst[idx] = (short)f2h_bits(v);
        }
        return;
    }

    if (blockIdx.x == 74) {
        for (int i = tid; i < BIAS_TOT; i += NT) {
            if (i >= BD && i < B4) continue;
            float v = 0.0f;
            if (i < B1)        { int o = i - BA;   if (o < 50)  v = b_input[o]; }
            else if (i < B2)   { int o = i - B1;   if (o < 75)  v = b_h1[o]; }
            else if (i < BEF)  { int o = i - B2;   if (o < 75)  v = b_h2[o]; }
            else if (i < BD)   { v = 0.0f; }
            else if (i < B5)   { int o = i - B4;   if (o < 125) v = b_h4[o]; }
            else if (i < BOUT) { int o = i - B5;   if (o < 50)  v = b_h5[o]; }
            else               { int o = i - BOUT; if (o < 3)   v = b_out[o]; }
            ws[i] = v;
        }
        return;
    }

    __shared__ __align__(16) float A[17500];
    __shared__ float B[675];
    __shared__ float C[256];
    __shared__ float Dd[256];
    __shared__ float Es[256];
    __shared__ float S[232];

    if (blockIdx.x == 71) {
        // ================= E chain =================
        stage(A, W_e2, 16875, tid);
        for (int i = tid; i < 225; i += NT) { Es[i] = W_e3[i]; C[i] = b_e1[i]; }
        __syncthreads();
        for (int o = tid; o < 675; o += NT) {
            int r = o / 225, c = o % 225;
            float s0 = 0.f, s1 = 0.f, s2 = 0.f;
#pragma unroll
            for (int t = 0; t < 75; t += 3) {
                s0 += Es[r * 75 + t]     * A[t * 225 + c];
                s1 += Es[r * 75 + t + 1] * A[(t + 1) * 225 + c];
                s2 += Es[r * 75 + t + 2] * A[(t + 2) * 225 + c];
            }
            B[o] = s0 + s1 + s2;
        }
        for (int o = tid; o < 75; o += NT) {
            float s0 = 0.f, s1 = 0.f, s2 = 0.f;
#pragma unroll
            for (int t = 0; t < 225; t += 3) {
                s0 += A[o * 225 + t]     * C[t];
                s1 += A[o * 225 + t + 1] * C[t + 1];
                s2 += A[o * 225 + t + 2] * C[t + 2];
            }
            Dd[o] = b_e2[o] + s0 + s1 + s2;
        }
        __syncthreads();
        stage(A, W_e1, 16875, tid);
        __syncthreads();
        for (int o = tid; o < 225; o += NT) {
            int r = o / 75, c = o % 75;
            float s0 = 0.f, s1 = 0.f, s2 = 0.f;
#pragma unroll
            for (int t = 0; t < 225; t += 3) {
                s0 += B[r * 225 + t]     * A[t * 75 + c];
                s1 += B[r * 225 + t + 1] * A[(t + 1) * 75 + c];
                s2 += B[r * 225 + t + 2] * A[(t + 2) * 75 + c];
            }
            S[o] = s0 + s1 + s2;
        }
        for (int o = tid; o < 16; o += NT) {   // be, zero-padded to 16
            float s = 0.0f;
            if (o < 3) {
                s = b_e3[o];
                for (int t = 0; t < 75; t++) s += Es[o * 75 + t] * Dd[t];
            }
            ws[STG_BE + o] = s;
        }
        __syncthreads();
        for (int i = tid; i < 3072; i += NT) {
            int j = i & 7, lane = (i >> 3) & 63, frag = i >> 9, pl = frag & 1, kt = frag >> 1;
            int n = lane & 15, k = kt * 32 + (lane >> 4) * 8 + j;
            float v = (n < 3 && k < 75) ? S[n * 75 + k] : 0.0f;
            float hi = h2f_bits(f2h_bits(v));
            wimg[W_EF + i] = (short)(pl ? f2h_bits(v - hi) : f2h_bits(v));
        }
    } else if (blockIdx.x == 72) {
        // ================= F chain =================
        stage(A,        W_f2, 7500, tid);
        stage(A + 7500, W_f1, 7500, tid);
        for (int i = tid; i < 150; i += NT) { Es[i] = W_f3[i]; C[i] = b_f1[i]; }
        __syncthreads();
        for (int o = tid; o < 450; o += NT) {
            int r = o / 150, c = o % 150;
            float s0 = 0.f, s1 = 0.f;
#pragma unroll
            for (int t = 0; t < 50; t += 2) {
                s0 += Es[r * 50 + t]     * A[t * 150 + c];
                s1 += Es[r * 50 + t + 1] * A[(t + 1) * 150 + c];
            }
            B[o] = s0 + s1;
        }
        for (int o = tid; o < 50; o += NT) {
            float s0 = 0.f, s1 = 0.f;
#pragma unroll
            for (int t = 0; t < 150; t += 2) {
                s0 += A[o * 150 + t]     * C[t];
                s1 += A[o * 150 + t + 1] * C[t + 1];
            }
            Dd[o] = b_f2[o] + s0 + s1;
        }
        __syncthreads();
        for (int o = tid; o < 150; o += NT) {
            int r = o / 50, c = o % 50;
            float s0 = 0.f, s1 = 0.f;
#pragma unroll
            for (int t = 0; t < 150; t += 2) {
                s0 += B[r * 150 + t]     * A[7500 + t * 50 + c];
                s1 += B[r * 150 + t + 1] * A[7500 + (t + 1) * 50 + c];
            }
            S[o] = s0 + s1;
        }
        for (int o = tid; o < 16; o += NT) {   // bf, zero-padded to 16
            float s = 0.0f;
            if (o < 3) {
                s = b_f3[o];
                for (int t = 0; t < 50; t++) s += Es[o * 50 + t] * Dd[t];
            }
            ws[STG_BF + o] = s;
        }
        __syncthreads();
        for (int i = tid; i < 2048; i += NT) {
            int j = i & 7, lane = (i >> 3) & 63, frag = i >> 9, pl = frag & 1, kt = frag >> 1;
            int n = lane & 15, k = kt * 32 + (lane >> 4) * 8 + j;
            float v = (n < 3 && k < 50) ? S[n * 50 + k] : 0.0f;
            float hi = h2f_bits(f2h_bits(v));
            wimg[W_EF + 3072 + i] = (short)(pl ? f2h_bits(v - hi) : f2h_bits(v));
        }
    } else {
        // ================= D chain =================
        stage(A,         W_d2, 7500, tid);
        stage(A + 7500,  W_d3, 7500, tid);
        stage(A + 15000, W_h3, 2500, tid);
        for (int i = tid; i < 150; i += NT) Es[i] = W_d1[i];
        for (int i = tid; i < 50;  i += NT) C[i] = b_d1[i];
        __syncthreads();
        for (int o = tid; o < 450; o += NT) {
            int r = o / 3, c = o % 3;
            float s0 = 0.f, s1 = 0.f;
#pragma unroll
            for (int t = 0; t < 50; t += 2) {
                s0 += A[r * 50 + t]     * Es[t * 3 + c];
                s1 += A[r * 50 + t + 1] * Es[(t + 1) * 3 + c];
            }
            B[o] = s0 + s1;
        }
        for (int o = tid; o < 150; o += NT) {
            float s0 = 0.f, s1 = 0.f;
#pragma unroll
            for (int t = 0; t < 50; t += 2) {
                s0 += A[o * 50 + t]     * C[t];
                s1 += A[o * 50 + t + 1] * C[t + 1];
            }
            Dd[o] = b_d2[o] + s0 + s1;
        }
        __syncthreads();
        for (int o = tid; o < 150; o += NT) {
            int r = o / 3, c = o % 3;
            float s0 = 0.f, s1 = 0.f;
#pragma unroll
            for (int t = 0; t < 150; t += 2) {
                s0 += A[7500 + r * 150 + t]     * B[t * 3 + c];
                s1 += A[7500 + r * 150 + t + 1] * B[(t + 1) * 3 + c];
            }
            Es[o] = s0 + s1;
        }
        for (int o = tid; o < 50; o += NT) {
            float s0 = 0.f, s1 = 0.f;
#pragma unroll
            for (int t = 0; t < 150; t += 2) {
                s0 += A[7500 + o * 150 + t]     * Dd[t];
                s1 += A[7500 + o * 150 + t + 1] * Dd[t + 1];
            }
            C[o] = b_d3[o] + s0 + s1;
        }
        __syncthreads();
        for (int o = tid; o < 150; o += NT) {
            int r = o / 3, c = o % 3;
            float s0 = 0.f, s1 = 0.f;
#pragma unroll
            for (int t = 0; t < 50; t += 2) {
                s0 += A[15000 + r * 50 + t]     * Es[t * 3 + c];
                s1 += A[15000 + r * 50 + t + 1] * Es[(t + 1) * 3 + c];
            }
            S[o] = s0 + s1;
        }
        for (int o = tid; o < 64; o += NT) {
            float v = 0.0f;
            if (o < 50) {
                float s0 = 0.f, s1 = 0.f;
#pragma unroll
                for (int t = 0; t < 50; t += 2) {
                    s0 += A[15000 + o * 50 + t]     * C[t];
                    s1 += A[15000 + o * 50 + t + 1] * C[t + 1];
                }
                v = b_h3[o] + s0 + s1;
            }
            ws[BD + o] = v;
        }
        __syncthreads();
        for (int i = tid; i < 4096; i += NT) {
            int j = i & 7, lane = (i >> 3) & 63, frag = i >> 9, pl = frag & 1, nt = frag >> 1;
            int n = nt * 16 + (lane & 15), k = (lane >> 4) * 8 + j;
            float v = (n < 50 && k < 3) ? S[n * 3 + k] : 0.0f;
            float hi = h2f_bits(f2h_bits(v));
            wimg[W_D + i] = (short)(pl ? f2h_bits(v - hi) : f2h_bits(v));
        }
    }
}

// ---------------------------------------------------------------------------
// main kernel helpers
// ---------------------------------------------------------------------------
__device__ __forceinline__ half8 gfragH(const short* __restrict__ wl, int off) {
    return *(const half8*)(wl + off);
}

__device__ __forceinline__ half8 readAf(const unsigned int* acts, int row0, int pane, int lane) {
    int m = lane & 15, qd = lane >> 4;
    const unsigned int* p = &acts[(row0 + m) * AST + pane + (qd & 1) * 8];
    uint4_ a = *(const uint4_*)p;
    uint4_ b = *(const uint4_*)(p + 4);
    unsigned sel = (qd >> 1) ? 0x07060302u : 0x05040100u;
    union { unsigned u[4]; half8 v; } r;
    r.u[0] = __builtin_amdgcn_perm(a.y, a.x, sel);
    r.u[1] = __builtin_amdgcn_perm(a.w, a.z, sel);
    r.u[2] = __builtin_amdgcn_perm(b.y, b.x, sel);
    r.u[3] = __builtin_amdgcn_perm(b.w, b.z, sel);
    return r.v;
}

__device__ __forceinline__ void writeCf(unsigned int* acts, int row0q, int dcol,
                                        f32x4 va, f32x4 vb) {
    unsigned int* p = &acts[row0q * AST + dcol];
#pragma unroll
    for (int r = 0; r < 4; r++) p[r * AST] = packh2(va[r], vb[r]);
}

__device__ __forceinline__ void t2s(f32x4& a0, f32x4& a1, half8 x0, half8 x1, half8 b) {
    a0 = MFMAH(x0, b, a0);
    a1 = MFMAH(x1, b, a1);
}
__device__ __forceinline__ void t2p(f32x4& a0, f32x4& a1, half8 x0, half8 x1,
                                    half8 bh, half8 bl) {
    a0 = MFMAH(x0, bh, a0);
    a1 = MFMAH(x1, bh, a1);
    a0 = MFMAH(x0, bl, a0);
    a1 = MFMAH(x1, bl, a1);
}

// ---------------------------------------------------------------------------
// main fused kernel: barrier-free after prologue; biases from global (L2)
// ---------------------------------------------------------------------------
__global__ __launch_bounds__(256, 3) void fused_mfma(
    const float* __restrict__ xin,
    const float* __restrict__ ws,
    float* __restrict__ out)
{
    __shared__ unsigned int acts[MTILE * AST];   // 26624 B (whole block LDS)

    const int tid = threadIdx.x;
    const int wv = tid >> 6;
    const int lane = tid & 63;
    const int qd = lane >> 4;
    const int mcol = lane & 15;
    const int rw = wv * 32;
    const short* __restrict__ wl = (const short*)(ws + BIAS_TOT) + lane * 8;
    const f32x4 zero4 = {0.f, 0.f, 0.f, 0.f};

    const int g0 = blockIdx.x * MTILE;
    const int bb = g0 / HW;
    const int p0 = g0 - bb * HW;
    const int yb = p0 / IW;
    const int xblk = p0 - yb * IW;
    const float* __restrict__ xb = xin + bb * 3 * HW;

    float* patch = (float*)acts;
    int*   stab  = (int*)(acts + 1984);

    for (int e = tid; e < 1980; e += 256) {
        int cr = e / 132;
        int i  = e - cr * 132;
        int c  = cr / 5, r = cr - c * 5;
        int ty = yb + r - 2; ty = ty < 0 ? -ty : ty; ty = (766 - ty) < ty ? 766 - ty : ty;
        int tx = xblk - 2 + i; tx = tx < 0 ? -tx : tx; tx = (766 - tx) < tx ? 766 - tx : tx;
        patch[cr * 132 + i] = xb[c * HW + ty * IW + tx];
    }
    if (tid < 96) {
        int v = 0;
        if (tid < 75) {
            int c = tid / 25, rem = tid - 25 * c;
            int rr = rem / 5, ss = rem - 5 * rr;
            v = (c * 5 + rr) * 132 + ss;
        }
        stab[tid] = v;
    }
    __syncthreads();

    // build sw fragments from LDS patch
    half8 swf[3][2];
    {
        int st[3][8];
#pragma unroll
        for (int kt = 0; kt < 3; kt++)
#pragma unroll
            for (int j = 0; j < 8; j++)
                st[kt][j] = stab[kt * 32 + qd * 8 + j];
#pragma unroll
        for (int mt = 0; mt < 2; mt++) {
            const int xloc = wv * 32 + mt * 16 + mcol;
#pragma unroll
            for (int kt = 0; kt < 3; kt++) {
                union { unsigned u32[4]; half8 v; } u;
#pragma unroll
                for (int jj = 0; jj < 8; jj += 2) {
                    float v0 = patch[st[kt][jj]     + xloc];
                    float v1 = patch[st[kt][jj + 1] + xloc];
                    if (kt == 2) {
                        int qq0 = 64 + qd * 8 + jj;
                        v0 = (qq0     < 75) ? v0 : 0.0f;
                        v1 = (qq0 + 1 < 75) ? v1 : 0.0f;
                    }
                    u.u32[jj >> 1] = packh2(v0, v1);
                }
                swf[kt][mt] = u.v;
            }
        }
    }
    __syncthreads();     // protect patch before acts writes; last barrier.

    // ===== layer A =====
    f32x4 accA[4][2];
#pragma unroll
    for (int nt = 0; nt < 4; nt++) { accA[nt][0] = zero4; accA[nt][1] = zero4; }
#pragma unroll
    for (int nt = 0; nt < 4; nt++)
        t2s(accA[nt][0], accA[nt][1], swf[0][0], swf[0][1], gfragH(wl, W_A0 + nt * 512));
#pragma unroll
    for (int nt = 0; nt < 4; nt++)
        t2s(accA[nt][0], accA[nt][1], swf[1][0], swf[1][1], gfragH(wl, W_A1 + nt * 512));
#pragma unroll
    for (int nt = 0; nt < 4; nt++)
        t2s(accA[nt][0], accA[nt][1], swf[2][0], swf[2][1], gfragH(wl, W_A2 + nt * 512));

    f32x4 x1C[4][2];
    half8 x1f[2][2];
#pragma unroll
    for (int nt = 0; nt < 4; nt++) {
        float bv = ws[BA + nt * 16 + mcol];
#pragma unroll
        for (int mt = 0; mt < 2; mt++) {
            f32x4 v = accA[nt][mt];
            v[0] += bv; v[1] += bv; v[2] += bv; v[3] += bv;
            x1C[nt][mt] = v;
        }
    }
#pragma unroll
    for (int mt = 0; mt < 2; mt++) {
        writeCf(acts, rw + mt * 16 + qd * 4, mcol,      x1C[0][mt], x1C[1][mt]);
        writeCf(acts, rw + mt * 16 + qd * 4, 16 + mcol, x1C[2][mt], x1C[3][mt]);
    }
#pragma unroll
    for (int kt = 0; kt < 2; kt++)
#pragma unroll
        for (int mt = 0; mt < 2; mt++)
            x1f[kt][mt] = readAf(acts, rw + mt * 16, kt * 16, lane);

    // ===== h1 =====
    f32x4 acc1[5][2];
#pragma unroll
    for (int nt = 0; nt < 5; nt++) { acc1[nt][0] = zero4; acc1[nt][1] = zero4; }
#pragma unroll
    for (int nt = 0; nt < 5; nt++)
        t2s(acc1[nt][0], acc1[nt][1], x1f[0][0], x1f[0][1], gfragH(wl, W_H1A + nt * 512));
#pragma unroll
    for (int nt = 0; nt < 5; nt++)
        t2s(acc1[nt][0], acc1[nt][1], x1f[1][0], x1f[1][1], gfragH(wl, W_H1B + nt * 512));
#pragma unroll
    for (int mt = 0; mt < 2; mt++) {
        f32x4 w5[5];
#pragma unroll
        for (int nt = 0; nt < 5; nt++) {
            float bv = ws[B1 + nt * 16 + mcol];
            f32x4 v = acc1[nt][mt];
            v[0] = lrelu(v[0] + bv); v[1] = lrelu(v[1] + bv);
            v[2] = lrelu(v[2] + bv); v[3] = lrelu(v[3] + bv);
            w5[nt] = v;
        }
        writeCf(acts, rw + mt * 16 + qd * 4, mcol,      w5[0], w5[1]);
        writeCf(acts, rw + mt * 16 + qd * 4, 16 + mcol, w5[2], w5[3]);
        writeCf(acts, rw + mt * 16 + qd * 4, 32 + mcol, w5[4], zero4);
    }

    // ===== h2 =====
    f32x4 acc2[5][2];
#pragma unroll
    for (int nt = 0; nt < 5; nt++) { acc2[nt][0] = zero4; acc2[nt][1] = zero4; }
    {
        half8 a0 = readAf(acts, rw, 0, lane), a1 = readAf(acts, rw + 16, 0, lane);
#pragma unroll
        for (int nt = 0; nt < 5; nt++)
            t2s(acc2[nt][0], acc2[nt][1], a0, a1, gfragH(wl, W_H2A + nt * 512));
    }
    {
        half8 a0 = readAf(acts, rw, 16, lane), a1 = readAf(acts, rw + 16, 16, lane);
#pragma unroll
        for (int nt = 0; nt < 5; nt++)
            t2s(acc2[nt][0], acc2[nt][1], a0, a1, gfragH(wl, W_H2B + nt * 512));
    }
    {
        half8 a0 = readAf(acts, rw, 32, lane), a1 = readAf(acts, rw + 16, 32, lane);
#pragma unroll
        for (int nt = 0; nt < 5; nt++)
            t2s(acc2[nt][0], acc2[nt][1], a0, a1, gfragH(wl, W_H2C + nt * 512));
    }
#pragma unroll
    for (int mt = 0; mt < 2; mt++) {
        f32x4 w5[5];
#pragma unroll
        for (int nt = 0; nt < 5; nt++) {
            float bv = ws[B2 + nt * 16 + mcol];
            f32x4 v = acc2[nt][mt];
            v[0] = tanh_fast(v[0] + bv); v[1] = tanh_fast(v[1] + bv);
            v[2] = tanh_fast(v[2] + bv); v[3] = tanh_fast(v[3] + bv);
            w5[nt] = v;
        }
        writeCf(acts, rw + mt * 16 + qd * 4, mcol,      w5[0], w5[1]);
        writeCf(acts, rw + mt * 16 + qd * 4, 16 + mcol, w5[2], w5[3]);
        writeCf(acts, rw + mt * 16 + qd * 4, 32 + mcol, w5[4], zero4);
    }

    // ===== EF =====
    f32x4 accEF[2];
    {
        float bv = ws[STG_BE + mcol] + ws[STG_BF + mcol];
        accEF[0] = (f32x4){bv, bv, bv, bv};
        accEF[1] = accEF[0];
    }
#pragma unroll
    for (int kt = 0; kt < 3; kt++) {
        half8 a0 = readAf(acts, rw, kt * 16, lane), a1 = readAf(acts, rw + 16, kt * 16, lane);
        t2p(accEF[0], accEF[1], a0, a1,
            gfragH(wl, W_EF + kt * 1024), gfragH(wl, W_EF + kt * 1024 + 512));
    }
#pragma unroll
    for (int kt = 0; kt < 2; kt++)
        t2p(accEF[0], accEF[1], x1f[kt][0], x1f[kt][1],
            gfragH(wl, W_EF + 3072 + kt * 1024), gfragH(wl, W_EF + 3072 + kt * 1024 + 512));
    half8 x4f[2];
#pragma unroll
    for (int mt = 0; mt < 2; mt++) {
        f32x4 v = accEF[mt];
        v[0] = lrelu(v[0]); v[1] = lrelu(v[1]); v[2] = lrelu(v[2]); v[3] = lrelu(v[3]);
        writeCf(acts, rw + mt * 16 + qd * 4, 32 + mcol, v, zero4);
    }
    x4f[0] = readAf(acts, rw, 32, lane);
    x4f[1] = readAf(acts, rw + 16, 32, lane);

    // ===== D =====
    f32x4 accD[4][2];
#pragma unroll
    for (int nt = 0; nt < 4; nt++) {
        float bv = ws[BD + nt * 16 + mcol];
        accD[nt][0] = (f32x4){bv, bv, bv, bv};
        accD[nt][1] = accD[nt][0];
    }
#pragma unroll
    for (int nt = 0; nt < 4; nt++)
        t2p(accD[nt][0], accD[nt][1], x4f[0], x4f[1],
            gfragH(wl, W_D + nt * 1024), gfragH(wl, W_D + nt * 1024 + 512));
#pragma unroll
    for (int mt = 0; mt < 2; mt++) {
        writeCf(acts, rw + mt * 16 + qd * 4, mcol,      accD[0][mt], accD[1][mt]);
        writeCf(acts, rw + mt * 16 + qd * 4, 16 + mcol, accD[2][mt], accD[3][mt]);
    }
    half8 xdf[2][2];
#pragma unroll
    for (int kt = 0; kt < 2; kt++)
#pragma unroll
        for (int mt = 0; mt < 2; mt++)
            xdf[kt][mt] = readAf(acts, rw + mt * 16, kt * 16, lane);

    f32x4 x6a[4][2];
#pragma unroll
    for (int nt = 0; nt < 4; nt++) {
        float bv = ws[B5 + nt * 16 + mcol];
#pragma unroll
        for (int mt = 0; mt < 2; mt++) {
            f32x4 v;
            v[0] = bv - x1C[nt][mt][0]; v[1] = bv - x1C[nt][mt][1];
            v[2] = bv - x1C[nt][mt][2]; v[3] = bv - x1C[nt][mt][3];
            x6a[nt][mt] = v;
        }
    }

    // ===== h4/h5 chunks =====
#pragma unroll 1
    for (int c = 0; c < 4; c++) {
        f32x4 acc5[2][2];
#pragma unroll
        for (int nt2 = 0; nt2 < 2; nt2++) {
            float bv = ws[B4 + c * 32 + nt2 * 16 + mcol];
            acc5[nt2][0] = (f32x4){bv, bv, bv, bv};
            acc5[nt2][1] = acc5[nt2][0];
        }
#pragma unroll
        for (int nt2 = 0; nt2 < 2; nt2++)
#pragma unroll
            for (int kt = 0; kt < 2; kt++)
                t2s(acc5[nt2][0], acc5[nt2][1], xdf[kt][0], xdf[kt][1],
                    gfragH(wl, W_H4C0 + c * 4096 + (nt2 * 2 + kt) * 512));
#pragma unroll
        for (int mt = 0; mt < 2; mt++) {
            f32x4 v0 = acc5[0][mt], v1 = acc5[1][mt];
            v0[0] = tanh_fast(v0[0]); v0[1] = tanh_fast(v0[1]);
            v0[2] = tanh_fast(v0[2]); v0[3] = tanh_fast(v0[3]);
            v1[0] = tanh_fast(v1[0]); v1[1] = tanh_fast(v1[1]);
            v1[2] = tanh_fast(v1[2]); v1[3] = tanh_fast(v1[3]);
            writeCf(acts, rw + mt * 16 + qd * 4, 32 + mcol, v0, v1);
        }
        half8 chf[2];
        chf[0] = readAf(acts, rw, 32, lane);
        chf[1] = readAf(acts, rw + 16, 32, lane);
#pragma unroll
        for (int nt = 0; nt < 4; nt++)
            t2s(x6a[nt][0], x6a[nt][1], chf[0], chf[1],
                gfragH(wl, W_H5C0 + c * 4096 + nt * 512));
    }

    // ===== out =====
#pragma unroll
    for (int mt = 0; mt < 2; mt++) {
        writeCf(acts, rw + mt * 16 + qd * 4, mcol,      x6a[0][mt], x6a[1][mt]);
        writeCf(acts, rw + mt * 16 + qd * 4, 16 + mcol, x6a[2][mt], x6a[3][mt]);
    }
    f32x4 accO[2];
    {
        float bv = ws[BOUT + mcol];
        accO[0] = (f32x4){bv, bv, bv, bv};
        accO[1] = accO[0];
    }
#pragma unroll
    for (int kt = 0; kt < 2; kt++) {
        half8 a0 = readAf(acts, rw, kt * 16, lane), a1 = readAf(acts, rw + 16, kt * 16, lane);
        t2s(accO[0], accO[1], a0, a1, gfragH(wl, W_OUT + kt * 512));
    }
    if (mcol < 3) {
#pragma unroll
        for (int mt = 0; mt < 2; mt++) {
#pragma unroll
            for (int r = 0; r < 4; r++) {
                int p = p0 + wv * 32 + mt * 16 + qd * 4 + r;
                out[(bb * 3 + mcol) * HW + p] = lrelu(accO[mt][r]);
            }
        }
    }
}

extern "C" void kernel_launch(void* const* d_in, const int* in_sizes, int n_in,
                              void* d_out, int out_size, void* d_ws, size_t ws_size,
                              hipStream_t stream)
{
    const float* xin = (const float*)d_in[0];
    float* ws = (float*)d_ws;

    setup_all<<<75, 256, 0, stream>>>(
        (const float*)d_in[1],  (const float*)d_in[2],   // input
        (const float*)d_in[3],  (const float*)d_in[4],   // h1
        (const float*)d_in[5],  (const float*)d_in[6],   // h2
        (const float*)d_in[7],  (const float*)d_in[8],   // h3
        (const float*)d_in[9],  (const float*)d_in[10],  // h4
        (const float*)d_in[11], (const float*)d_in[12],  // h5
        (const float*)d_in[13], (const float*)d_in[14],  // out
        (const float*)d_in[15], (const float*)d_in[16],  // e1
        (const float*)d_in[17], (const float*)d_in[18],  // e2
        (const float*)d_in[19], (const float*)d_in[20],  // e3
        (const float*)d_in[21], (const float*)d_in[22],  // f1
        (const float*)d_in[23], (const float*)d_in[24],  // f2
        (const float*)d_in[25], (const float*)d_in[26],  // f3
        (const float*)d_in[27], (const float*)d_in[28],  // d1
        (const float*)d_in[29], (const float*)d_in[30],  // d2
        (const float*)d_in[31], (const float*)d_in[32],  // d3
        ws);

    fused_mfma<<<NBLK, 256, 0, stream>>>(xin, ws, (float*)d_out);
}

// Round 14
// 229.310 us; speedup vs baseline: 1.0097x; 1.0097x over previous
//
#include <hip/hip_runtime.h>

// ---------------------------------------------------------------------------
// Round 14 = Round 13 with x1C eliminated:
//  - x6a init (b5 - x1, C layout) is computed by MFMA of x1f (A-layout fp16,
//    already live) against a NEGATED IDENTITY weight image (4 frags) -> the
//    32-VGPR x1C array disappears from the live set.
//  - __launch_bounds__(256, 4): with the smaller live set the wave should fit
//    <=128 unified regs -> 4 waves/SIMD. WRITE_SIZE is the spill check.
// ---------------------------------------------------------------------------

#define IW 384
#define HW (384 * 384)           // 147456
#define NPIX (4 * HW)            // 589824
#define MTILE 128
#define NBLK (NPIX / MTILE)      // 4608
#define AST 52                   // acts row stride in dwords (48 data + 4 pad)

typedef _Float16 half8 __attribute__((ext_vector_type(8)));
typedef __fp16 fp16x2 __attribute__((ext_vector_type(2)));
typedef __attribute__((ext_vector_type(4))) float f32x4;
typedef __attribute__((ext_vector_type(4))) unsigned int uint4_;

#define MFMAH(A, B, C) __builtin_amdgcn_mfma_f32_16x16x32_f16((A), (B), (C), 0, 0, 0)

// bias table offsets (dwords in ws)
#define BA   0
#define B1   64
#define B2   144
#define BEF  224
#define BD   240
#define B4   304
#define B5   432
#define BOUT 496
#define BIAS_TOT 512

// weight image segment offsets (shorts, after bias table). frag = 512 shorts.
#define W_A0   0
#define W_A1   2048
#define W_A2   4096
#define W_H1A  6144
#define W_H1B  8704
#define W_H2A  11264
#define W_H2B  13824
#define W_H2C  16384
#define W_EF   18944    // E: 6 frags hi/lo (kt-major), F: 4 frags at +3072
#define W_D    24064    // 8 frags hi/lo (nt-major)
#define W_H4C0 28160    // chunk c: h4 at 28160+c*4096
#define W_H5C0 30208    //          h5 at 30208+c*4096
#define W_OUT  44544
#define W_NI   45568    // negated identity: 4 frags (nt, kt=nt>>1 baked)
#define W_TOT  47616

// be / bf slots (dword offsets, after images): 16 entries each, zero-padded
#define STG_BE  24320   // = BIAS_TOT/..., placed after images: 512 + 47616/2 = 24320
#define STG_BF  24336

__device__ __forceinline__ float lrelu(float v) { return v >= 0.0f ? v : 0.01f * v; }

__device__ __forceinline__ float tanh_fast(float v) {
    float e = __expf(2.0f * v);
    return 1.0f - 2.0f * __builtin_amdgcn_rcpf(e + 1.0f);
}

__device__ __forceinline__ unsigned short f2h_bits(float v) {
    union { _Float16 h; unsigned short s; } u; u.h = (_Float16)v; return u.s;
}
__device__ __forceinline__ float h2f_bits(unsigned short s) {
    union { _Float16 h; unsigned short s; } u; u.s = s; return (float)u.h;
}
__device__ __forceinline__ unsigned packh2(float a, float b) {
    union { fp16x2 h; unsigned u; } u;
    u.h = __builtin_amdgcn_cvt_pkrtz(a, b);
    return u.u;
}

// deep-pipelined global->LDS staging: float4 x unroll-4
__device__ __forceinline__ void stage(float* dst, const float* __restrict__ src,
                                      int n, int tid) {
    int n4 = n >> 2;
    float4* d = (float4*)dst;
    const float4* s = (const float4*)src;
#pragma unroll 4
    for (int i = tid; i < n4; i += 256) d[i] = s[i];
    for (int i = (n4 << 2) + tid; i < n; i += 256) dst[i] = src[i];
}

// ---------------------------------------------------------------------------
// setup_all: 75 independent blocks x 256 threads.
// ---------------------------------------------------------------------------
__global__ __launch_bounds__(256) void setup_all(
    const float* __restrict__ W_input, const float* __restrict__ b_input,
    const float* __restrict__ W_h1,  const float* __restrict__ b_h1,
    const float* __restrict__ W_h2,  const float* __restrict__ b_h2,
    const float* __restrict__ W_h3,  const float* __restrict__ b_h3,
    const float* __restrict__ W_h4,  const float* __restrict__ b_h4,
    const float* __restrict__ W_h5,  const float* __restrict__ b_h5,
    const float* __restrict__ W_out, const float* __restrict__ b_out,
    const float* __restrict__ W_e1,  const float* __restrict__ b_e1,
    const float* __restrict__ W_e2,  const float* __restrict__ b_e2,
    const float* __restrict__ W_e3,  const float* __restrict__ b_e3,
    const float* __restrict__ W_f1,  const float* __restrict__ b_f1,
    const float* __restrict__ W_f2,  const float* __restrict__ b_f2,
    const float* __restrict__ W_f3,  const float* __restrict__ b_f3,
    const float* __restrict__ W_d1,  const float* __restrict__ b_d1,
    const float* __restrict__ W_d2,  const float* __restrict__ b_d2,
    const float* __restrict__ W_d3,  const float* __restrict__ b_d3,
    float* __restrict__ ws)
{
    const int tid = threadIdx.x;
    const int NT = 256;
    short* wimg = (short*)(ws + BIAS_TOT);

    if (blockIdx.x < 71) {
        const int soff[17] = {W_A0,W_A1,W_A2, W_H1A,W_H1B, W_H2A,W_H2B,W_H2C,
                              W_H4C0,W_H5C0, W_H4C0+4096,W_H5C0+4096,
                              W_H4C0+8192,W_H5C0+8192, W_H4C0+12288,W_H5C0+12288,
                              W_OUT};
        const int slay[17] = {0,0,0, 1,1, 2,2,2, 6,7, 6,7, 6,7, 6,7, 8};
        const int sNT[17]  = {4,4,4, 5,5, 5,5,5, 2,4, 2,4, 2,4, 2,4, 1};
        const int sKTS[17] = {1,1,1, 1,1, 1,1,1, 2,1, 2,1, 2,1, 2,1, 2};
        const int snb[17]  = {0,0,0, 0,0, 0,0,0, 0,0, 32,0, 64,0, 96,0, 0};
        const int skb[17]  = {0,32,64, 0,32, 0,32,64, 0,0, 0,32, 0,64, 0,96, 0};

        int seg = 0, local = blockIdx.x;
        while (seg < 16 && local >= sNT[seg] * sKTS[seg]) { local -= sNT[seg] * sKTS[seg]; seg++; }
        const int kts = sKTS[seg];
        const int kt = local % kts, nt = local / kts;
        const int lay = slay[seg];
        short* dst = wimg + soff[seg] + local * 512;

#pragma unroll
        for (int t = 0; t < 2; t++) {
            int idx = tid + t * 256;
            int j = idx & 7, lane = idx >> 3;
            int n = snb[seg] + nt * 16 + (lane & 15);
            int k = skb[seg] + kt * 32 + (lane >> 4) * 8 + j;
            float v = 0.0f;
            switch (lay) {
                case 0: if (n < 50  && k < 75)  v = W_input[n * 75 + k]; break;
                case 1: if (n < 75  && k < 50)  v = W_h1[n * 50 + k]; break;
                case 2: if (n < 75  && k < 75)  v = W_h2[n * 75 + k]; break;
                case 6: if (n < 125 && k < 50)  v = W_h4[n * 50 + k]; break;
                case 7: if (n < 50  && k < 125) v = W_h5[n * 125 + k]; break;
                case 8: if (n < 3   && k < 50)  v = W_out[n * 50 + k]; break;
            }
            dst[idx] = (short)f2h_bits(v);
        }
        return;
    }

    if (blockIdx.x == 74) {
        for (int i = tid; i < BIAS_TOT; i += NT) {
            if (i >= BD && i < B4) continue;
            float v = 0.0f;
            if (i < B1)        { int o = i - BA;   if (o < 50)  v = b_input[o]; }
            else if (i < B2)   { int o = i - B1;   if (o < 75)  v = b_h1[o]; }
            else if (i < BEF)  { int o = i - B2;   if (o < 75)  v = b_h2[o]; }
            else if (i < BD)   { v = 0.0f; }
            else if (i < B5)   { int o = i - B4;   if (o < 125) v = b_h4[o]; }
            else if (i < BOUT) { int o = i - B5;   if (o < 50)  v = b_h5[o]; }
            else               { int o = i - BOUT; if (o < 3)   v = b_out[o]; }
            ws[i] = v;
        }
        // negated-identity frags: frag nt, B[k][n] = -(k==n), kt=nt>>1 baked
        for (int i = tid; i < 2048; i += NT) {
            int j = i & 7, lane = (i >> 3) & 63, nt = i >> 9;
            int n = nt * 16 + (lane & 15);
            int k = (nt >> 1) * 32 + (lane >> 4) * 8 + j;
            wimg[W_NI + i] = (short)f2h_bits(k == n ? -1.0f : 0.0f);
        }
        return;
    }

    __shared__ __align__(16) float A[17500];
    __shared__ float B[675];
    __shared__ float C[256];
    __shared__ float Dd[256];
    __shared__ float Es[256];
    __shared__ float S[232];

    if (blockIdx.x == 71) {
        // ================= E chain =================
        stage(A, W_e2, 16875, tid);
        for (int i = tid; i < 225; i += NT) { Es[i] = W_e3[i]; C[i] = b_e1[i]; }
        __syncthreads();
        for (int o = tid; o < 675; o += NT) {
            int r = o / 225, c = o % 225;
            float s0 = 0.f, s1 = 0.f, s2 = 0.f;
#pragma unroll
            for (int t = 0; t < 75; t += 3) {
                s0 += Es[r * 75 + t]     * A[t * 225 + c];
                s1 += Es[r * 75 + t + 1] * A[(t + 1) * 225 + c];
                s2 += Es[r * 75 + t + 2] * A[(t + 2) * 225 + c];
            }
            B[o] = s0 + s1 + s2;
        }
        for (int o = tid; o < 75; o += NT) {
            float s0 = 0.f, s1 = 0.f, s2 = 0.f;
#pragma unroll
            for (int t = 0; t < 225; t += 3) {
                s0 += A[o * 225 + t]     * C[t];
                s1 += A[o * 225 + t + 1] * C[t + 1];
                s2 += A[o * 225 + t + 2] * C[t + 2];
            }
            Dd[o] = b_e2[o] + s0 + s1 + s2;
        }
        __syncthreads();
        stage(A, W_e1, 16875, tid);
        __syncthreads();
        for (int o = tid; o < 225; o += NT) {
            int r = o / 75, c = o % 75;
            float s0 = 0.f, s1 = 0.f, s2 = 0.f;
#pragma unroll
            for (int t = 0; t < 225; t += 3) {
                s0 += B[r * 225 + t]     * A[t * 75 + c];
                s1 += B[r * 225 + t + 1] * A[(t + 1) * 75 + c];
                s2 += B[r * 225 + t + 2] * A[(t + 2) * 75 + c];
            }
            S[o] = s0 + s1 + s2;
        }
        for (int o = tid; o < 16; o += NT) {
            float s = 0.0f;
            if (o < 3) {
                s = b_e3[o];
                for (int t = 0; t < 75; t++) s += Es[o * 75 + t] * Dd[t];
            }
            ws[STG_BE + o] = s;
        }
        __syncthreads();
        for (int i = tid; i < 3072; i += NT) {
            int j = i & 7, lane = (i >> 3) & 63, frag = i >> 9, pl = frag & 1, kt = frag >> 1;
            int n = lane & 15, k = kt * 32 + (lane >> 4) * 8 + j;
            float v = (n < 3 && k < 75) ? S[n * 75 + k] : 0.0f;
            float hi = h2f_bits(f2h_bits(v));
            wimg[W_EF + i] = (short)(pl ? f2h_bits(v - hi) : f2h_bits(v));
        }
    } else if (blockIdx.x == 72) {
        // ================= F chain =================
        stage(A,        W_f2, 7500, tid);
        stage(A + 7500, W_f1, 7500, tid);
        for (int i = tid; i < 150; i += NT) { Es[i] = W_f3[i]; C[i] = b_f1[i]; }
        __syncthreads();
        for (int o = tid; o < 450; o += NT) {
            int r = o / 150, c = o % 150;
            float s0 = 0.f, s1 = 0.f;
#pragma unroll
            for (int t = 0; t < 50; t += 2) {
                s0 += Es[r * 50 + t]     * A[t * 150 + c];
                s1 += Es[r * 50 + t + 1] * A[(t + 1) * 150 + c];
            }
            B[o] = s0 + s1;
        }
        for (int o = tid; o < 50; o += NT) {
            float s0 = 0.f, s1 = 0.f;
#pragma unroll
            for (int t = 0; t < 150; t += 2) {
                s0 += A[o * 150 + t]     * C[t];
                s1 += A[o * 150 + t + 1] * C[t + 1];
            }
            Dd[o] = b_f2[o] + s0 + s1;
        }
        __syncthreads();
        for (int o = tid; o < 150; o += NT) {
            int r = o / 50, c = o % 50;
            float s0 = 0.f, s1 = 0.f;
#pragma unroll
            for (int t = 0; t < 150; t += 2) {
                s0 += B[r * 150 + t]     * A[7500 + t * 50 + c];
                s1 += B[r * 150 + t + 1] * A[7500 + (t + 1) * 50 + c];
            }
            S[o] = s0 + s1;
        }
        for (int o = tid; o < 16; o += NT) {
            float s = 0.0f;
            if (o < 3) {
                s = b_f3[o];
                for (int t = 0; t < 50; t++) s += Es[o * 50 + t] * Dd[t];
            }
            ws[STG_BF + o] = s;
        }
        __syncthreads();
        for (int i = tid; i < 2048; i += NT) {
            int j = i & 7, lane = (i >> 3) & 63, frag = i >> 9, pl = frag & 1, kt = frag >> 1;
            int n = lane & 15, k = kt * 32 + (lane >> 4) * 8 + j;
            float v = (n < 3 && k < 50) ? S[n * 50 + k] : 0.0f;
            float hi = h2f_bits(f2h_bits(v));
            wimg[W_EF + 3072 + i] = (short)(pl ? f2h_bits(v - hi) : f2h_bits(v));
        }
    } else {
        // ================= D chain =================
        stage(A,         W_d2, 7500, tid);
        stage(A + 7500,  W_d3, 7500, tid);
        stage(A + 15000, W_h3, 2500, tid);
        for (int i = tid; i < 150; i += NT) Es[i] = W_d1[i];
        for (int i = tid; i < 50;  i += NT) C[i] = b_d1[i];
        __syncthreads();
        for (int o = tid; o < 450; o += NT) {
            int r = o / 3, c = o % 3;
            float s0 = 0.f, s1 = 0.f;
#pragma unroll
            for (int t = 0; t < 50; t += 2) {
                s0 += A[r * 50 + t]     * Es[t * 3 + c];
                s1 += A[r * 50 + t + 1] * Es[(t + 1) * 3 + c];
            }
            B[o] = s0 + s1;
        }
        for (int o = tid; o < 150; o += NT) {
            float s0 = 0.f, s1 = 0.f;
#pragma unroll
            for (int t = 0; t < 50; t += 2) {
                s0 += A[o * 50 + t]     * C[t];
                s1 += A[o * 50 + t + 1] * C[t + 1];
            }
            Dd[o] = b_d2[o] + s0 + s1;
        }
        __syncthreads();
        for (int o = tid; o < 150; o += NT) {
            int r = o / 3, c = o % 3;
            float s0 = 0.f, s1 = 0.f;
#pragma unroll
            for (int t = 0; t < 150; t += 2) {
                s0 += A[7500 + r * 150 + t]     * B[t * 3 + c];
                s1 += A[7500 + r * 150 + t + 1] * B[(t + 1) * 3 + c];
            }
            Es[o] = s0 + s1;
        }
        for (int o = tid; o < 50; o += NT) {
            float s0 = 0.f, s1 = 0.f;
#pragma unroll
            for (int t = 0; t < 150; t += 2) {
                s0 += A[7500 + o * 150 + t]     * Dd[t];
                s1 += A[7500 + o * 150 + t + 1] * Dd[t + 1];
            }
            C[o] = b_d3[o] + s0 + s1;
        }
        __syncthreads();
        for (int o = tid; o < 150; o += NT) {
            int r = o / 3, c = o % 3;
            float s0 = 0.f, s1 = 0.f;
#pragma unroll
            for (int t = 0; t < 50; t += 2) {
                s0 += A[15000 + r * 50 + t]     * Es[t * 3 + c];
                s1 += A[15000 + r * 50 + t + 1] * Es[(t + 1) * 3 + c];
            }
            S[o] = s0 + s1;
        }
        for (int o = tid; o < 64; o += NT) {
            float v = 0.0f;
            if (o < 50) {
                float s0 = 0.f, s1 = 0.f;
#pragma unroll
                for (int t = 0; t < 50; t += 2) {
                    s0 += A[15000 + o * 50 + t]     * C[t];
                    s1 += A[15000 + o * 50 + t + 1] * C[t + 1];
                }
                v = b_h3[o] + s0 + s1;
            }
            ws[BD + o] = v;
        }
        __syncthreads();
        for (int i = tid; i < 4096; i += NT) {
            int j = i & 7, lane = (i >> 3) & 63, frag = i >> 9, pl = frag & 1, nt = frag >> 1;
            int n = nt * 16 + (lane & 15), k = (lane >> 4) * 8 + j;
            float v = (n < 50 && k < 3) ? S[n * 3 + k] : 0.0f;
            float hi = h2f_bits(f2h_bits(v));
            wimg[W_D + i] = (short)(pl ? f2h_bits(v - hi) : f2h_bits(v));
        }
    }
}

// ---------------------------------------------------------------------------
// main kernel helpers
// ---------------------------------------------------------------------------
__device__ __forceinline__ half8 gfragH(const short* __restrict__ wl, int off) {
    return *(const half8*)(wl + off);
}

__device__ __forceinline__ half8 readAf(const unsigned int* acts, int row0, int pane, int lane) {
    int m = lane & 15, qd = lane >> 4;
    const unsigned int* p = &acts[(row0 + m) * AST + pane + (qd & 1) * 8];
    uint4_ a = *(const uint4_*)p;
    uint4_ b = *(const uint4_*)(p + 4);
    unsigned sel = (qd >> 1) ? 0x07060302u : 0x05040100u;
    union { unsigned u[4]; half8 v; } r;
    r.u[0] = __builtin_amdgcn_perm(a.y, a.x, sel);
    r.u[1] = __builtin_amdgcn_perm(a.w, a.z, sel);
    r.u[2] = __builtin_amdgcn_perm(b.y, b.x, sel);
    r.u[3] = __builtin_amdgcn_perm(b.w, b.z, sel);
    return r.v;
}

__device__ __forceinline__ void writeCf(unsigned int* acts, int row0q, int dcol,
                                        f32x4 va, f32x4 vb) {
    unsigned int* p = &acts[row0q * AST + dcol];
#pragma unroll
    for (int r = 0; r < 4; r++) p[r * AST] = packh2(va[r], vb[r]);
}

__device__ __forceinline__ void t2s(f32x4& a0, f32x4& a1, half8 x0, half8 x1, half8 b) {
    a0 = MFMAH(x0, b, a0);
    a1 = MFMAH(x1, b, a1);
}
__device__ __forceinline__ void t2p(f32x4& a0, f32x4& a1, half8 x0, half8 x1,
                                    half8 bh, half8 bl) {
    a0 = MFMAH(x0, bh, a0);
    a1 = MFMAH(x1, bh, a1);
    a0 = MFMAH(x0, bl, a0);
    a1 = MFMAH(x1, bl, a1);
}

// ---------------------------------------------------------------------------
// main fused kernel: barrier-free after prologue; biases from global (L2)
// ---------------------------------------------------------------------------
__global__ __launch_bounds__(256, 4) void fused_mfma(
    const float* __restrict__ xin,
    const float* __restrict__ ws,
    float* __restrict__ out)
{
    __shared__ unsigned int acts[MTILE * AST];   // 26624 B

    const int tid = threadIdx.x;
    const int wv = tid >> 6;
    const int lane = tid & 63;
    const int qd = lane >> 4;
    const int mcol = lane & 15;
    const int rw = wv * 32;
    const short* __restrict__ wl = (const short*)(ws + BIAS_TOT) + lane * 8;
    const f32x4 zero4 = {0.f, 0.f, 0.f, 0.f};

    const int g0 = blockIdx.x * MTILE;
    const int bb = g0 / HW;
    const int p0 = g0 - bb * HW;
    const int yb = p0 / IW;
    const int xblk = p0 - yb * IW;
    const float* __restrict__ xb = xin + bb * 3 * HW;

    float* patch = (float*)acts;
    int*   stab  = (int*)(acts + 1984);

    for (int e = tid; e < 1980; e += 256) {
        int cr = e / 132;
        int i  = e - cr * 132;
        int c  = cr / 5, r = cr - c * 5;
        int ty = yb + r - 2; ty = ty < 0 ? -ty : ty; ty = (766 - ty) < ty ? 766 - ty : ty;
        int tx = xblk - 2 + i; tx = tx < 0 ? -tx : tx; tx = (766 - tx) < tx ? 766 - tx : tx;
        patch[cr * 132 + i] = xb[c * HW + ty * IW + tx];
    }
    if (tid < 96) {
        int v = 0;
        if (tid < 75) {
            int c = tid / 25, rem = tid - 25 * c;
            int rr = rem / 5, ss = rem - 5 * rr;
            v = (c * 5 + rr) * 132 + ss;
        }
        stab[tid] = v;
    }
    __syncthreads();

    // build sw fragments from LDS patch (k>=75 taps multiply zero weights)
    half8 swf[3][2];
    {
        int st[3][8];
#pragma unroll
        for (int kt = 0; kt < 3; kt++)
#pragma unroll
            for (int j = 0; j < 8; j++)
                st[kt][j] = stab[kt * 32 + qd * 8 + j];
#pragma unroll
        for (int mt = 0; mt < 2; mt++) {
            const int xloc = wv * 32 + mt * 16 + mcol;
#pragma unroll
            for (int kt = 0; kt < 3; kt++) {
                union { unsigned u32[4]; half8 v; } u;
#pragma unroll
                for (int jj = 0; jj < 8; jj += 2) {
                    float v0 = patch[st[kt][jj]     + xloc];
                    float v1 = patch[st[kt][jj + 1] + xloc];
                    if (kt == 2) {
                        int qq0 = 64 + qd * 8 + jj;
                        v0 = (qq0     < 75) ? v0 : 0.0f;
                        v1 = (qq0 + 1 < 75) ? v1 : 0.0f;
                    }
                    u.u32[jj >> 1] = packh2(v0, v1);
                }
                swf[kt][mt] = u.v;
            }
        }
    }
    __syncthreads();     // protect patch before acts writes; last barrier.

    // ===== layer A =====
    f32x4 accA[4][2];
#pragma unroll
    for (int nt = 0; nt < 4; nt++) { accA[nt][0] = zero4; accA[nt][1] = zero4; }
#pragma unroll
    for (int nt = 0; nt < 4; nt++)
        t2s(accA[nt][0], accA[nt][1], swf[0][0], swf[0][1], gfragH(wl, W_A0 + nt * 512));
#pragma unroll
    for (int nt = 0; nt < 4; nt++)
        t2s(accA[nt][0], accA[nt][1], swf[1][0], swf[1][1], gfragH(wl, W_A1 + nt * 512));
#pragma unroll
    for (int nt = 0; nt < 4; nt++)
        t2s(accA[nt][0], accA[nt][1], swf[2][0], swf[2][1], gfragH(wl, W_A2 + nt * 512));

    half8 x1f[2][2];
#pragma unroll
    for (int nt = 0; nt < 4; nt++) {
        float bv = ws[BA + nt * 16 + mcol];
#pragma unroll
        for (int mt = 0; mt < 2; mt++) {
            accA[nt][mt][0] += bv; accA[nt][mt][1] += bv;
            accA[nt][mt][2] += bv; accA[nt][mt][3] += bv;
        }
    }
#pragma unroll
    for (int mt = 0; mt < 2; mt++) {
        writeCf(acts, rw + mt * 16 + qd * 4, mcol,      accA[0][mt], accA[1][mt]);
        writeCf(acts, rw + mt * 16 + qd * 4, 16 + mcol, accA[2][mt], accA[3][mt]);
    }
#pragma unroll
    for (int kt = 0; kt < 2; kt++)
#pragma unroll
        for (int mt = 0; mt < 2; mt++)
            x1f[kt][mt] = readAf(acts, rw + mt * 16, kt * 16, lane);

    // ===== h1 =====
    f32x4 acc1[5][2];
#pragma unroll
    for (int nt = 0; nt < 5; nt++) { acc1[nt][0] = zero4; acc1[nt][1] = zero4; }
#pragma unroll
    for (int nt = 0; nt < 5; nt++)
        t2s(acc1[nt][0], acc1[nt][1], x1f[0][0], x1f[0][1], gfragH(wl, W_H1A + nt * 512));
#pragma unroll
    for (int nt = 0; nt < 5; nt++)
        t2s(acc1[nt][0], acc1[nt][1], x1f[1][0], x1f[1][1], gfragH(wl, W_H1B + nt * 512));
#pragma unroll
    for (int mt = 0; mt < 2; mt++) {
        f32x4 w5[5];
#pragma unroll
        for (int nt = 0; nt < 5; nt++) {
            float bv = ws[B1 + nt * 16 + mcol];
            f32x4 v = acc1[nt][mt];
            v[0] = lrelu(v[0] + bv); v[1] = lrelu(v[1] + bv);
            v[2] = lrelu(v[2] + bv); v[3] = lrelu(v[3] + bv);
            w5[nt] = v;
        }
        writeCf(acts, rw + mt * 16 + qd * 4, mcol,      w5[0], w5[1]);
        writeCf(acts, rw + mt * 16 + qd * 4, 16 + mcol, w5[2], w5[3]);
        writeCf(acts, rw + mt * 16 + qd * 4, 32 + mcol, w5[4], zero4);
    }

    // ===== h2 =====
    f32x4 acc2[5][2];
#pragma unroll
    for (int nt = 0; nt < 5; nt++) { acc2[nt][0] = zero4; acc2[nt][1] = zero4; }
    {
        half8 a0 = readAf(acts, rw, 0, lane), a1 = readAf(acts, rw + 16, 0, lane);
#pragma unroll
        for (int nt = 0; nt < 5; nt++)
            t2s(acc2[nt][0], acc2[nt][1], a0, a1, gfragH(wl, W_H2A + nt * 512));
    }
    {
        half8 a0 = readAf(acts, rw, 16, lane), a1 = readAf(acts, rw + 16, 16, lane);
#pragma unroll
        for (int nt = 0; nt < 5; nt++)
            t2s(acc2[nt][0], acc2[nt][1], a0, a1, gfragH(wl, W_H2B + nt * 512));
    }
    {
        half8 a0 = readAf(acts, rw, 32, lane), a1 = readAf(acts, rw + 16, 32, lane);
#pragma unroll
        for (int nt = 0; nt < 5; nt++)
            t2s(acc2[nt][0], acc2[nt][1], a0, a1, gfragH(wl, W_H2C + nt * 512));
    }
#pragma unroll
    for (int mt = 0; mt < 2; mt++) {
        f32x4 w5[5];
#pragma unroll
        for (int nt = 0; nt < 5; nt++) {
            float bv = ws[B2 + nt * 16 + mcol];
            f32x4 v = acc2[nt][mt];
            v[0] = tanh_fast(v[0] + bv); v[1] = tanh_fast(v[1] + bv);
            v[2] = tanh_fast(v[2] + bv); v[3] = tanh_fast(v[3] + bv);
            w5[nt] = v;
        }
        writeCf(acts, rw + mt * 16 + qd * 4, mcol,      w5[0], w5[1]);
        writeCf(acts, rw + mt * 16 + qd * 4, 16 + mcol, w5[2], w5[3]);
        writeCf(acts, rw + mt * 16 + qd * 4, 32 + mcol, w5[4], zero4);
    }

    // ===== EF =====
    f32x4 accEF[2];
    {
        float bv = ws[STG_BE + mcol] + ws[STG_BF + mcol];
        accEF[0] = (f32x4){bv, bv, bv, bv};
        accEF[1] = accEF[0];
    }
#pragma unroll
    for (int kt = 0; kt < 3; kt++) {
        half8 a0 = readAf(acts, rw, kt * 16, lane), a1 = readAf(acts, rw + 16, kt * 16, lane);
        t2p(accEF[0], accEF[1], a0, a1,
            gfragH(wl, W_EF + kt * 1024), gfragH(wl, W_EF + kt * 1024 + 512));
    }
#pragma unroll
    for (int kt = 0; kt < 2; kt++)
        t2p(accEF[0], accEF[1], x1f[kt][0], x1f[kt][1],
            gfragH(wl, W_EF + 3072 + kt * 1024), gfragH(wl, W_EF + 3072 + kt * 1024 + 512));
    half8 x4f[2];
#pragma unroll
    for (int mt = 0; mt < 2; mt++) {
        f32x4 v = accEF[mt];
        v[0] = lrelu(v[0]); v[1] = lrelu(v[1]); v[2] = lrelu(v[2]); v[3] = lrelu(v[3]);
        writeCf(acts, rw + mt * 16 + qd * 4, 32 + mcol, v, zero4);
    }
    x4f[0] = readAf(acts, rw, 32, lane);
    x4f[1] = readAf(acts, rw + 16, 32, lane);

    // ===== D =====
    f32x4 accD[4][2];
#pragma unroll
    for (int nt = 0; nt < 4; nt++) {
        float bv = ws[BD + nt * 16 + mcol];
        accD[nt][0] = (f32x4){bv, bv, bv, bv};
        accD[nt][1] = accD[nt][0];
    }
#pragma unroll
    for (int nt = 0; nt < 4; nt++)
        t2p(accD[nt][0], accD[nt][1], x4f[0], x4f[1],
            gfragH(wl, W_D + nt * 1024), gfragH(wl, W_D + nt * 1024 + 512));
#pragma unroll
    for (int mt = 0; mt < 2; mt++) {
        writeCf(acts, rw + mt * 16 + qd * 4, mcol,      accD[0][mt], accD[1][mt]);
        writeCf(acts, rw + mt * 16 + qd * 4, 16 + mcol, accD[2][mt], accD[3][mt]);
    }
    half8 xdf[2][2];
#pragma unroll
    for (int kt = 0; kt < 2; kt++)
#pragma unroll
        for (int mt = 0; mt < 2; mt++)
            xdf[kt][mt] = readAf(acts, rw + mt * 16, kt * 16, lane);

    // x6a init: b5 - x1, via MFMA of x1f against negated identity (C-layout)
    f32x4 x6a[4][2];
#pragma unroll
    for (int nt = 0; nt < 4; nt++) {
        float bv = ws[B5 + nt * 16 + mcol];
        half8 nI = gfragH(wl, W_NI + nt * 512);
#pragma unroll
        for (int mt = 0; mt < 2; mt++) {
            f32x4 v = {bv, bv, bv, bv};
            x6a[nt][mt] = MFMAH(x1f[nt >> 1][mt], nI, v);
        }
    }

    // ===== h4/h5 chunks =====
#pragma unroll 1
    for (int c = 0; c < 4; c++) {
        f32x4 acc5[2][2];
#pragma unroll
        for (int nt2 = 0; nt2 < 2; nt2++) {
            float bv = ws[B4 + c * 32 + nt2 * 16 + mcol];
            acc5[nt2][0] = (f32x4){bv, bv, bv, bv};
            acc5[nt2][1] = acc5[nt2][0];
        }
#pragma unroll
        for (int nt2 = 0; nt2 < 2; nt2++)
#pragma unroll
            for (int kt = 0; kt < 2; kt++)
                t2s(acc5[nt2][0], acc5[nt2][1], xdf[kt][0], xdf[kt][1],
                    gfragH(wl, W_H4C0 + c * 4096 + (nt2 * 2 + kt) * 512));
#pragma unroll
        for (int mt = 0; mt < 2; mt++) {
            f32x4 v0 = acc5[0][mt], v1 = acc5[1][mt];
            v0[0] = tanh_fast(v0[0]); v0[1] = tanh_fast(v0[1]);
            v0[2] = tanh_fast(v0[2]); v0[3] = tanh_fast(v0[3]);
            v1[0] = tanh_fast(v1[0]); v1[1] = tanh_fast(v1[1]);
            v1[2] = tanh_fast(v1[2]); v1[3] = tanh_fast(v1[3]);
            writeCf(acts, rw + mt * 16 + qd * 4, 32 + mcol, v0, v1);
        }
        half8 chf[2];
        chf[0] = readAf(acts, rw, 32, lane);
        chf[1] = readAf(acts, rw + 16, 32, lane);
#pragma unroll
        for (int nt = 0; nt < 4; nt++)
            t2s(x6a[nt][0], x6a[nt][1], chf[0], chf[1],
                gfragH(wl, W_H5C0 + c * 4096 + nt * 512));
    }

    // ===== out =====
#pragma unroll
    for (int mt = 0; mt < 2; mt++) {
        writeCf(acts, rw + mt * 16 + qd * 4, mcol,      x6a[0][mt], x6a[1][mt]);
        writeCf(acts, rw + mt * 16 + qd * 4, 16 + mcol, x6a[2][mt], x6a[3][mt]);
    }
    f32x4 accO[2];
    {
        float bv = ws[BOUT + mcol];
        accO[0] = (f32x4){bv, bv, bv, bv};
        accO[1] = accO[0];
    }
#pragma unroll
    for (int kt = 0; kt < 2; kt++) {
        half8 a0 = readAf(acts, rw, kt * 16, lane), a1 = readAf(acts, rw + 16, kt * 16, lane);
        t2s(accO[0], accO[1], a0, a1, gfragH(wl, W_OUT + kt * 512));
    }
    if (mcol < 3) {
#pragma unroll
        for (int mt = 0; mt < 2; mt++) {
#pragma unroll
            for (int r = 0; r < 4; r++) {
                int p = p0 + wv * 32 + mt * 16 + qd * 4 + r;
                out[(bb * 3 + mcol) * HW + p] = lrelu(accO[mt][r]);
            }
        }
    }
}

extern "C" void kernel_launch(void* const* d_in, const int* in_sizes, int n_in,
                              void* d_out, int out_size, void* d_ws, size_t ws_size,
                              hipStream_t stream)
{
    const float* xin = (const float*)d_in[0];
    float* ws = (float*)d_ws;

    setup_all<<<75, 256, 0, stream>>>(
        (const float*)d_in[1],  (const float*)d_in[2],   // input
        (const float*)d_in[3],  (const float*)d_in[4],   // h1
        (const float*)d_in[5],  (const float*)d_in[6],   // h2
        (const float*)d_in[7],  (const float*)d_in[8],   // h3
        (const float*)d_in[9],  (const float*)d_in[10],  // h4
        (const float*)d_in[11], (const float*)d_in[12],  // h5
        (const float*)d_in[13], (const float*)d_in[14],  // out
        (const float*)d_in[15], (const float*)d_in[16],  // e1
        (const float*)d_in[17], (const float*)d_in[18],  // e2
        (const float*)d_in[19], (const float*)d_in[20],  // e3
        (const float*)d_in[21], (const float*)d_in[22],  // f1
        (const float*)d_in[23], (const float*)d_in[24],  // f2
        (const float*)d_in[25], (const float*)d_in[26],  // f3
        (const float*)d_in[27], (const float*)d_in[28],  // d1
        (const float*)d_in[29], (const float*)d_in[30],  // d2
        (const float*)d_in[31], (const float*)d_in[32],  // d3
        ws);

    fused_mfma<<<NBLK, 256, 0, stream>>>(xin, ws, (float*)d_out);
}

// Round 15
// 226.934 us; speedup vs baseline: 1.0203x; 1.0105x over previous
//
#include <hip/hip_runtime.h>

// ---------------------------------------------------------------------------
// Round 15 = Round 14 with the h4/h5 chunk loop pipelined:
//  - scratch slot double-buffered (even chunks dcols 32-47, odd 48-63);
//    AST 52 -> 68 (LDS 34816 B, still 4 blocks/CU), removing the WAR hazard
//    that serialized consecutive chunks through one LDS slot.
//  - chunk loop fully unrolled so the scheduler overlaps chunk c+1's h4
//    MFMAs (depend only on xdf) with chunk c's tanh->LDS->read round trip.
// ---------------------------------------------------------------------------

#define IW 384
#define HW (384 * 384)           // 147456
#define NPIX (4 * HW)            // 589824
#define MTILE 128
#define NBLK (NPIX / MTILE)      // 4608
#define AST 68                   // acts row stride in dwords (64 data + 4 pad)

typedef _Float16 half8 __attribute__((ext_vector_type(8)));
typedef __fp16 fp16x2 __attribute__((ext_vector_type(2)));
typedef __attribute__((ext_vector_type(4))) float f32x4;
typedef __attribute__((ext_vector_type(4))) unsigned int uint4_;

#define MFMAH(A, B, C) __builtin_amdgcn_mfma_f32_16x16x32_f16((A), (B), (C), 0, 0, 0)

// bias table offsets (dwords in ws)
#define BA   0
#define B1   64
#define B2   144
#define BEF  224
#define BD   240
#define B4   304
#define B5   432
#define BOUT 496
#define BIAS_TOT 512

// weight image segment offsets (shorts, after bias table). frag = 512 shorts.
#define W_A0   0
#define W_A1   2048
#define W_A2   4096
#define W_H1A  6144
#define W_H1B  8704
#define W_H2A  11264
#define W_H2B  13824
#define W_H2C  16384
#define W_EF   18944    // E: 6 frags hi/lo (kt-major), F: 4 frags at +3072
#define W_D    24064    // 8 frags hi/lo (nt-major)
#define W_H4C0 28160    // chunk c: h4 at 28160+c*4096
#define W_H5C0 30208    //          h5 at 30208+c*4096
#define W_OUT  44544
#define W_NI   45568    // negated identity: 4 frags (nt, kt=nt>>1 baked)
#define W_TOT  47616

// be / bf slots (dword offsets, after images): 16 entries each, zero-padded
#define STG_BE  24320
#define STG_BF  24336

__device__ __forceinline__ float lrelu(float v) { return v >= 0.0f ? v : 0.01f * v; }

__device__ __forceinline__ float tanh_fast(float v) {
    float e = __expf(2.0f * v);
    return 1.0f - 2.0f * __builtin_amdgcn_rcpf(e + 1.0f);
}

__device__ __forceinline__ unsigned short f2h_bits(float v) {
    union { _Float16 h; unsigned short s; } u; u.h = (_Float16)v; return u.s;
}
__device__ __forceinline__ float h2f_bits(unsigned short s) {
    union { _Float16 h; unsigned short s; } u; u.s = s; return (float)u.h;
}
__device__ __forceinline__ unsigned packh2(float a, float b) {
    union { fp16x2 h; unsigned u; } u;
    u.h = __builtin_amdgcn_cvt_pkrtz(a, b);
    return u.u;
}

// deep-pipelined global->LDS staging: float4 x unroll-4
__device__ __forceinline__ void stage(float* dst, const float* __restrict__ src,
                                      int n, int tid) {
    int n4 = n >> 2;
    float4* d = (float4*)dst;
    const float4* s = (const float4*)src;
#pragma unroll 4
    for (int i = tid; i < n4; i += 256) d[i] = s[i];
    for (int i = (n4 << 2) + tid; i < n; i += 256) dst[i] = src[i];
}

// ---------------------------------------------------------------------------
// setup_all: 75 independent blocks x 256 threads. (identical to R14)
// ---------------------------------------------------------------------------
__global__ __launch_bounds__(256) void setup_all(
    const float* __restrict__ W_input, const float* __restrict__ b_input,
    const float* __restrict__ W_h1,  const float* __restrict__ b_h1,
    const float* __restrict__ W_h2,  const float* __restrict__ b_h2,
    const float* __restrict__ W_h3,  const float* __restrict__ b_h3,
    const float* __restrict__ W_h4,  const float* __restrict__ b_h4,
    const float* __restrict__ W_h5,  const float* __restrict__ b_h5,
    const float* __restrict__ W_out, const float* __restrict__ b_out,
    const float* __restrict__ W_e1,  const float* __restrict__ b_e1,
    const float* __restrict__ W_e2,  const float* __restrict__ b_e2,
    const float* __restrict__ W_e3,  const float* __restrict__ b_e3,
    const float* __restrict__ W_f1,  const float* __restrict__ b_f1,
    const float* __restrict__ W_f2,  const float* __restrict__ b_f2,
    const float* __restrict__ W_f3,  const float* __restrict__ b_f3,
    const float* __restrict__ W_d1,  const float* __restrict__ b_d1,
    const float* __restrict__ W_d2,  const float* __restrict__ b_d2,
    const float* __restrict__ W_d3,  const float* __restrict__ b_d3,
    float* __restrict__ ws)
{
    const int tid = threadIdx.x;
    const int NT = 256;
    short* wimg = (short*)(ws + BIAS_TOT);

    if (blockIdx.x < 71) {
        const int soff[17] = {W_A0,W_A1,W_A2, W_H1A,W_H1B, W_H2A,W_H2B,W_H2C,
                              W_H4C0,W_H5C0, W_H4C0+4096,W_H5C0+4096,
                              W_H4C0+8192,W_H5C0+8192, W_H4C0+12288,W_H5C0+12288,
                              W_OUT};
        const int slay[17] = {0,0,0, 1,1, 2,2,2, 6,7, 6,7, 6,7, 6,7, 8};
        const int sNT[17]  = {4,4,4, 5,5, 5,5,5, 2,4, 2,4, 2,4, 2,4, 1};
        const int sKTS[17] = {1,1,1, 1,1, 1,1,1, 2,1, 2,1, 2,1, 2,1, 2};
        const int snb[17]  = {0,0,0, 0,0, 0,0,0, 0,0, 32,0, 64,0, 96,0, 0};
        const int skb[17]  = {0,32,64, 0,32, 0,32,64, 0,0, 0,32, 0,64, 0,96, 0};

        int seg = 0, local = blockIdx.x;
        while (seg < 16 && local >= sNT[seg] * sKTS[seg]) { local -= sNT[seg] * sKTS[seg]; seg++; }
        const int kts = sKTS[seg];
        const int kt = local % kts, nt = local / kts;
        const int lay = slay[seg];
        short* dst = wimg + soff[seg] + local * 512;

#pragma unroll
        for (int t = 0; t < 2; t++) {
            int idx = tid + t * 256;
            int j = idx & 7, lane = idx >> 3;
            int n = snb[seg] + nt * 16 + (lane & 15);
            int k = skb[seg] + kt * 32 + (lane >> 4) * 8 + j;
            float v = 0.0f;
            switch (lay) {
                case 0: if (n < 50  && k < 75)  v = W_input[n * 75 + k]; break;
                case 1: if (n < 75  && k < 50)  v = W_h1[n * 50 + k]; break;
                case 2: if (n < 75  && k < 75)  v = W_h2[n * 75 + k]; break;
                case 6: if (n < 125 && k < 50)  v = W_h4[n * 50 + k]; break;
                case 7: if (n < 50  && k < 125) v = W_h5[n * 125 + k]; break;
                case 8: if (n < 3   && k < 50)  v = W_out[n * 50 + k]; break;
            }
            dst[idx] = (short)f2h_bits(v);
        }
        return;
    }

    if (blockIdx.x == 74) {
        for (int i = tid; i < BIAS_TOT; i += NT) {
            if (i >= BD && i < B4) continue;
            float v = 0.0f;
            if (i < B1)        { int o = i - BA;   if (o < 50)  v = b_input[o]; }
            else if (i < B2)   { int o = i - B1;   if (o < 75)  v = b_h1[o]; }
            else if (i < BEF)  { int o = i - B2;   if (o < 75)  v = b_h2[o]; }
            else if (i < BD)   { v = 0.0f; }
            else if (i < B5)   { int o = i - B4;   if (o < 125) v = b_h4[o]; }
            else if (i < BOUT) { int o = i - B5;   if (o < 50)  v = b_h5[o]; }
            else               { int o = i - BOUT; if (o < 3)   v = b_out[o]; }
            ws[i] = v;
        }
        for (int i = tid; i < 2048; i += NT) {
            int j = i & 7, lane = (i >> 3) & 63, nt = i >> 9;
            int n = nt * 16 + (lane & 15);
            int k = (nt >> 1) * 32 + (lane >> 4) * 8 + j;
            wimg[W_NI + i] = (short)f2h_bits(k == n ? -1.0f : 0.0f);
        }
        return;
    }

    __shared__ __align__(16) float A[17500];
    __shared__ float B[675];
    __shared__ float C[256];
    __shared__ float Dd[256];
    __shared__ float Es[256];
    __shared__ float S[232];

    if (blockIdx.x == 71) {
        // ================= E chain =================
        stage(A, W_e2, 16875, tid);
        for (int i = tid; i < 225; i += NT) { Es[i] = W_e3[i]; C[i] = b_e1[i]; }
        __syncthreads();
        for (int o = tid; o < 675; o += NT) {
            int r = o / 225, c = o % 225;
            float s0 = 0.f, s1 = 0.f, s2 = 0.f;
#pragma unroll
            for (int t = 0; t < 75; t += 3) {
                s0 += Es[r * 75 + t]     * A[t * 225 + c];
                s1 += Es[r * 75 + t + 1] * A[(t + 1) * 225 + c];
                s2 += Es[r * 75 + t + 2] * A[(t + 2) * 225 + c];
            }
            B[o] = s0 + s1 + s2;
        }
        for (int o = tid; o < 75; o += NT) {
            float s0 = 0.f, s1 = 0.f, s2 = 0.f;
#pragma unroll
            for (int t = 0; t < 225; t += 3) {
                s0 += A[o * 225 + t]     * C[t];
                s1 += A[o * 225 + t + 1] * C[t + 1];
                s2 += A[o * 225 + t + 2] * C[t + 2];
            }
            Dd[o] = b_e2[o] + s0 + s1 + s2;
        }
        __syncthreads();
        stage(A, W_e1, 16875, tid);
        __syncthreads();
        for (int o = tid; o < 225; o += NT) {
            int r = o / 75, c = o % 75;
            float s0 = 0.f, s1 = 0.f, s2 = 0.f;
#pragma unroll
            for (int t = 0; t < 225; t += 3) {
                s0 += B[r * 225 + t]     * A[t * 75 + c];
                s1 += B[r * 225 + t + 1] * A[(t + 1) * 75 + c];
                s2 += B[r * 225 + t + 2] * A[(t + 2) * 75 + c];
            }
            S[o] = s0 + s1 + s2;
        }
        for (int o = tid; o < 16; o += NT) {
            float s = 0.0f;
            if (o < 3) {
                s = b_e3[o];
                for (int t = 0; t < 75; t++) s += Es[o * 75 + t] * Dd[t];
            }
            ws[STG_BE + o] = s;
        }
        __syncthreads();
        for (int i = tid; i < 3072; i += NT) {
            int j = i & 7, lane = (i >> 3) & 63, frag = i >> 9, pl = frag & 1, kt = frag >> 1;
            int n = lane & 15, k = kt * 32 + (lane >> 4) * 8 + j;
            float v = (n < 3 && k < 75) ? S[n * 75 + k] : 0.0f;
            float hi = h2f_bits(f2h_bits(v));
            wimg[W_EF + i] = (short)(pl ? f2h_bits(v - hi) : f2h_bits(v));
        }
    } else if (blockIdx.x == 72) {
        // ================= F chain =================
        stage(A,        W_f2, 7500, tid);
        stage(A + 7500, W_f1, 7500, tid);
        for (int i = tid; i < 150; i += NT) { Es[i] = W_f3[i]; C[i] = b_f1[i]; }
        __syncthreads();
        for (int o = tid; o < 450; o += NT) {
            int r = o / 150, c = o % 150;
            float s0 = 0.f, s1 = 0.f;
#pragma unroll
            for (int t = 0; t < 50; t += 2) {
                s0 += Es[r * 50 + t]     * A[t * 150 + c];
                s1 += Es[r * 50 + t + 1] * A[(t + 1) * 150 + c];
            }
            B[o] = s0 + s1;
        }
        for (int o = tid; o < 50; o += NT) {
            float s0 = 0.f, s1 = 0.f;
#pragma unroll
            for (int t = 0; t < 150; t += 2) {
                s0 += A[o * 150 + t]     * C[t];
                s1 += A[o * 150 + t + 1] * C[t + 1];
            }
            Dd[o] = b_f2[o] + s0 + s1;
        }
        __syncthreads();
        for (int o = tid; o < 150; o += NT) {
            int r = o / 50, c = o % 50;
            float s0 = 0.f, s1 = 0.f;
#pragma unroll
            for (int t = 0; t < 150; t += 2) {
                s0 += B[r * 150 + t]     * A[7500 + t * 50 + c];
                s1 += B[r * 150 + t + 1] * A[7500 + (t + 1) * 50 + c];
            }
            S[o] = s0 + s1;
        }
        for (int o = tid; o < 16; o += NT) {
            float s = 0.0f;
            if (o < 3) {
                s = b_f3[o];
                for (int t = 0; t < 50; t++) s += Es[o * 50 + t] * Dd[t];
            }
            ws[STG_BF + o] = s;
        }
        __syncthreads();
        for (int i = tid; i < 2048; i += NT) {
            int j = i & 7, lane = (i >> 3) & 63, frag = i >> 9, pl = frag & 1, kt = frag >> 1;
            int n = lane & 15, k = kt * 32 + (lane >> 4) * 8 + j;
            float v = (n < 3 && k < 50) ? S[n * 50 + k] : 0.0f;
            float hi = h2f_bits(f2h_bits(v));
            wimg[W_EF + 3072 + i] = (short)(pl ? f2h_bits(v - hi) : f2h_bits(v));
        }
    } else {
        // ================= D chain =================
        stage(A,         W_d2, 7500, tid);
        stage(A + 7500,  W_d3, 7500, tid);
        stage(A + 15000, W_h3, 2500, tid);
        for (int i = tid; i < 150; i += NT) Es[i] = W_d1[i];
        for (int i = tid; i < 50;  i += NT) C[i] = b_d1[i];
        __syncthreads();
        for (int o = tid; o < 450; o += NT) {
            int r = o / 3, c = o % 3;
            float s0 = 0.f, s1 = 0.f;
#pragma unroll
            for (int t = 0; t < 50; t += 2) {
                s0 += A[r * 50 + t]     * Es[t * 3 + c];
                s1 += A[r * 50 + t + 1] * Es[(t + 1) * 3 + c];
            }
            B[o] = s0 + s1;
        }
        for (int o = tid; o < 150; o += NT) {
            float s0 = 0.f, s1 = 0.f;
#pragma unroll
            for (int t = 0; t < 50; t += 2) {
                s0 += A[o * 50 + t]     * C[t];
                s1 += A[o * 50 + t + 1] * C[t + 1];
            }
            Dd[o] = b_d2[o] + s0 + s1;
        }
        __syncthreads();
        for (int o = tid; o < 150; o += NT) {
            int r = o / 3, c = o % 3;
            float s0 = 0.f, s1 = 0.f;
#pragma unroll
            for (int t = 0; t < 150; t += 2) {
                s0 += A[7500 + r * 150 + t]     * B[t * 3 + c];
                s1 += A[7500 + r * 150 + t + 1] * B[(t + 1) * 3 + c];
            }
            Es[o] = s0 + s1;
        }
        for (int o = tid; o < 50; o += NT) {
            float s0 = 0.f, s1 = 0.f;
#pragma unroll
            for (int t = 0; t < 150; t += 2) {
                s0 += A[7500 + o * 150 + t]     * Dd[t];
                s1 += A[7500 + o * 150 + t + 1] * Dd[t + 1];
            }
            C[o] = b_d3[o] + s0 + s1;
        }
        __syncthreads();
        for (int o = tid; o < 150; o += NT) {
            int r = o / 3, c = o % 3;
            float s0 = 0.f, s1 = 0.f;
#pragma unroll
            for (int t = 0; t < 50; t += 2) {
                s0 += A[15000 + r * 50 + t]     * Es[t * 3 + c];
                s1 += A[15000 + r * 50 + t + 1] * Es[(t + 1) * 3 + c];
            }
            S[o] = s0 + s1;
        }
        for (int o = tid; o < 64; o += NT) {
            float v = 0.0f;
            if (o < 50) {
                float s0 = 0.f, s1 = 0.f;
#pragma unroll
                for (int t = 0; t < 50; t += 2) {
                    s0 += A[15000 + o * 50 + t]     * C[t];
                    s1 += A[15000 + o * 50 + t + 1] * C[t + 1];
                }
                v = b_h3[o] + s0 + s1;
            }
            ws[BD + o] = v;
        }
        __syncthreads();
        for (int i = tid; i < 4096; i += NT) {
            int j = i & 7, lane = (i >> 3) & 63, frag = i >> 9, pl = frag & 1, nt = frag >> 1;
            int n = nt * 16 + (lane & 15), k = (lane >> 4) * 8 + j;
            float v = (n < 50 && k < 3) ? S[n * 3 + k] : 0.0f;
            float hi = h2f_bits(f2h_bits(v));
            wimg[W_D + i] = (short)(pl ? f2h_bits(v - hi) : f2h_bits(v));
        }
    }
}

// ---------------------------------------------------------------------------
// main kernel helpers
// ---------------------------------------------------------------------------
__device__ __forceinline__ half8 gfragH(const short* __restrict__ wl, int off) {
    return *(const half8*)(wl + off);
}

__device__ __forceinline__ half8 readAf(const unsigned int* acts, int row0, int pane, int lane) {
    int m = lane & 15, qd = lane >> 4;
    const unsigned int* p = &acts[(row0 + m) * AST + pane + (qd & 1) * 8];
    uint4_ a = *(const uint4_*)p;
    uint4_ b = *(const uint4_*)(p + 4);
    unsigned sel = (qd >> 1) ? 0x07060302u : 0x05040100u;
    union { unsigned u[4]; half8 v; } r;
    r.u[0] = __builtin_amdgcn_perm(a.y, a.x, sel);
    r.u[1] = __builtin_amdgcn_perm(a.w, a.z, sel);
    r.u[2] = __builtin_amdgcn_perm(b.y, b.x, sel);
    r.u[3] = __builtin_amdgcn_perm(b.w, b.z, sel);
    return r.v;
}

__device__ __forceinline__ void writeCf(unsigned int* acts, int row0q, int dcol,
                                        f32x4 va, f32x4 vb) {
    unsigned int* p = &acts[row0q * AST + dcol];
#pragma unroll
    for (int r = 0; r < 4; r++) p[r * AST] = packh2(va[r], vb[r]);
}

__device__ __forceinline__ void t2s(f32x4& a0, f32x4& a1, half8 x0, half8 x1, half8 b) {
    a0 = MFMAH(x0, b, a0);
    a1 = MFMAH(x1, b, a1);
}
__device__ __forceinline__ void t2p(f32x4& a0, f32x4& a1, half8 x0, half8 x1,
                                    half8 bh, half8 bl) {
    a0 = MFMAH(x0, bh, a0);
    a1 = MFMAH(x1, bh, a1);
    a0 = MFMAH(x0, bl, a0);
    a1 = MFMAH(x1, bl, a1);
}

// ---------------------------------------------------------------------------
// main fused kernel: barrier-free after prologue; biases from global (L2)
// ---------------------------------------------------------------------------
__global__ __launch_bounds__(256, 4) void fused_mfma(
    const float* __restrict__ xin,
    const float* __restrict__ ws,
    float* __restrict__ out)
{
    __shared__ unsigned int acts[MTILE * AST];   // 34816 B

    const int tid = threadIdx.x;
    const int wv = tid >> 6;
    const int lane = tid & 63;
    const int qd = lane >> 4;
    const int mcol = lane & 15;
    const int rw = wv * 32;
    const short* __restrict__ wl = (const short*)(ws + BIAS_TOT) + lane * 8;
    const f32x4 zero4 = {0.f, 0.f, 0.f, 0.f};

    const int g0 = blockIdx.x * MTILE;
    const int bb = g0 / HW;
    const int p0 = g0 - bb * HW;
    const int yb = p0 / IW;
    const int xblk = p0 - yb * IW;
    const float* __restrict__ xb = xin + bb * 3 * HW;

    float* patch = (float*)acts;
    int*   stab  = (int*)(acts + 1984);

    for (int e = tid; e < 1980; e += 256) {
        int cr = e / 132;
        int i  = e - cr * 132;
        int c  = cr / 5, r = cr - c * 5;
        int ty = yb + r - 2; ty = ty < 0 ? -ty : ty; ty = (766 - ty) < ty ? 766 - ty : ty;
        int tx = xblk - 2 + i; tx = tx < 0 ? -tx : tx; tx = (766 - tx) < tx ? 766 - tx : tx;
        patch[cr * 132 + i] = xb[c * HW + ty * IW + tx];
    }
    if (tid < 96) {
        int v = 0;
        if (tid < 75) {
            int c = tid / 25, rem = tid - 25 * c;
            int rr = rem / 5, ss = rem - 5 * rr;
            v = (c * 5 + rr) * 132 + ss;
        }
        stab[tid] = v;
    }
    __syncthreads();

    // build sw fragments from LDS patch
    half8 swf[3][2];
    {
        int st[3][8];
#pragma unroll
        for (int kt = 0; kt < 3; kt++)
#pragma unroll
            for (int j = 0; j < 8; j++)
                st[kt][j] = stab[kt * 32 + qd * 8 + j];
#pragma unroll
        for (int mt = 0; mt < 2; mt++) {
            const int xloc = wv * 32 + mt * 16 + mcol;
#pragma unroll
            for (int kt = 0; kt < 3; kt++) {
                union { unsigned u32[4]; half8 v; } u;
#pragma unroll
                for (int jj = 0; jj < 8; jj += 2) {
                    float v0 = patch[st[kt][jj]     + xloc];
                    float v1 = patch[st[kt][jj + 1] + xloc];
                    if (kt == 2) {
                        int qq0 = 64 + qd * 8 + jj;
                        v0 = (qq0     < 75) ? v0 : 0.0f;
                        v1 = (qq0 + 1 < 75) ? v1 : 0.0f;
                    }
                    u.u32[jj >> 1] = packh2(v0, v1);
                }
                swf[kt][mt] = u.v;
            }
        }
    }
    __syncthreads();     // protect patch before acts writes; last barrier.

    // ===== layer A =====
    f32x4 accA[4][2];
#pragma unroll
    for (int nt = 0; nt < 4; nt++) { accA[nt][0] = zero4; accA[nt][1] = zero4; }
#pragma unroll
    for (int nt = 0; nt < 4; nt++)
        t2s(accA[nt][0], accA[nt][1], swf[0][0], swf[0][1], gfragH(wl, W_A0 + nt * 512));
#pragma unroll
    for (int nt = 0; nt < 4; nt++)
        t2s(accA[nt][0], accA[nt][1], swf[1][0], swf[1][1], gfragH(wl, W_A1 + nt * 512));
#pragma unroll
    for (int nt = 0; nt < 4; nt++)
        t2s(accA[nt][0], accA[nt][1], swf[2][0], swf[2][1], gfragH(wl, W_A2 + nt * 512));

    half8 x1f[2][2];
#pragma unroll
    for (int nt = 0; nt < 4; nt++) {
        float bv = ws[BA + nt * 16 + mcol];
#pragma unroll
        for (int mt = 0; mt < 2; mt++) {
            accA[nt][mt][0] += bv; accA[nt][mt][1] += bv;
            accA[nt][mt][2] += bv; accA[nt][mt][3] += bv;
        }
    }
#pragma unroll
    for (int mt = 0; mt < 2; mt++) {
        writeCf(acts, rw + mt * 16 + qd * 4, mcol,      accA[0][mt], accA[1][mt]);
        writeCf(acts, rw + mt * 16 + qd * 4, 16 + mcol, accA[2][mt], accA[3][mt]);
    }
#pragma unroll
    for (int kt = 0; kt < 2; kt++)
#pragma unroll
        for (int mt = 0; mt < 2; mt++)
            x1f[kt][mt] = readAf(acts, rw + mt * 16, kt * 16, lane);

    // ===== h1 =====
    f32x4 acc1[5][2];
#pragma unroll
    for (int nt = 0; nt < 5; nt++) { acc1[nt][0] = zero4; acc1[nt][1] = zero4; }
#pragma unroll
    for (int nt = 0; nt < 5; nt++)
        t2s(acc1[nt][0], acc1[nt][1], x1f[0][0], x1f[0][1], gfragH(wl, W_H1A + nt * 512));
#pragma unroll
    for (int nt = 0; nt < 5; nt++)
        t2s(acc1[nt][0], acc1[nt][1], x1f[1][0], x1f[1][1], gfragH(wl, W_H1B + nt * 512));
#pragma unroll
    for (int mt = 0; mt < 2; mt++) {
        f32x4 w5[5];
#pragma unroll
        for (int nt = 0; nt < 5; nt++) {
            float bv = ws[B1 + nt * 16 + mcol];
            f32x4 v = acc1[nt][mt];
            v[0] = lrelu(v[0] + bv); v[1] = lrelu(v[1] + bv);
            v[2] = lrelu(v[2] + bv); v[3] = lrelu(v[3] + bv);
            w5[nt] = v;
        }
        writeCf(acts, rw + mt * 16 + qd * 4, mcol,      w5[0], w5[1]);
        writeCf(acts, rw + mt * 16 + qd * 4, 16 + mcol, w5[2], w5[3]);
        writeCf(acts, rw + mt * 16 + qd * 4, 32 + mcol, w5[4], zero4);
    }

    // ===== h2 =====
    f32x4 acc2[5][2];
#pragma unroll
    for (int nt = 0; nt < 5; nt++) { acc2[nt][0] = zero4; acc2[nt][1] = zero4; }
    {
        half8 a0 = readAf(acts, rw, 0, lane), a1 = readAf(acts, rw + 16, 0, lane);
#pragma unroll
        for (int nt = 0; nt < 5; nt++)
            t2s(acc2[nt][0], acc2[nt][1], a0, a1, gfragH(wl, W_H2A + nt * 512));
    }
    {
        half8 a0 = readAf(acts, rw, 16, lane), a1 = readAf(acts, rw + 16, 16, lane);
#pragma unroll
        for (int nt = 0; nt < 5; nt++)
            t2s(acc2[nt][0], acc2[nt][1], a0, a1, gfragH(wl, W_H2B + nt * 512));
    }
    {
        half8 a0 = readAf(acts, rw, 32, lane), a1 = readAf(acts, rw + 16, 32, lane);
#pragma unroll
        for (int nt = 0; nt < 5; nt++)
            t2s(acc2[nt][0], acc2[nt][1], a0, a1, gfragH(wl, W_H2C + nt * 512));
    }
#pragma unroll
    for (int mt = 0; mt < 2; mt++) {
        f32x4 w5[5];
#pragma unroll
        for (int nt = 0; nt < 5; nt++) {
            float bv = ws[B2 + nt * 16 + mcol];
            f32x4 v = acc2[nt][mt];
            v[0] = tanh_fast(v[0] + bv); v[1] = tanh_fast(v[1] + bv);
            v[2] = tanh_fast(v[2] + bv); v[3] = tanh_fast(v[3] + bv);
            w5[nt] = v;
        }
        writeCf(acts, rw + mt * 16 + qd * 4, mcol,      w5[0], w5[1]);
        writeCf(acts, rw + mt * 16 + qd * 4, 16 + mcol, w5[2], w5[3]);
        writeCf(acts, rw + mt * 16 + qd * 4, 32 + mcol, w5[4], zero4);
    }

    // ===== EF =====
    f32x4 accEF[2];
    {
        float bv = ws[STG_BE + mcol] + ws[STG_BF + mcol];
        accEF[0] = (f32x4){bv, bv, bv, bv};
        accEF[1] = accEF[0];
    }
#pragma unroll
    for (int kt = 0; kt < 3; kt++) {
        half8 a0 = readAf(acts, rw, kt * 16, lane), a1 = readAf(acts, rw + 16, kt * 16, lane);
        t2p(accEF[0], accEF[1], a0, a1,
            gfragH(wl, W_EF + kt * 1024), gfragH(wl, W_EF + kt * 1024 + 512));
    }
#pragma unroll
    for (int kt = 0; kt < 2; kt++)
        t2p(accEF[0], accEF[1], x1f[kt][0], x1f[kt][1],
            gfragH(wl, W_EF + 3072 + kt * 1024), gfragH(wl, W_EF + 3072 + kt * 1024 + 512));
    half8 x4f[2];
#pragma unroll
    for (int mt = 0; mt < 2; mt++) {
        f32x4 v = accEF[mt];
        v[0] = lrelu(v[0]); v[1] = lrelu(v[1]); v[2] = lrelu(v[2]); v[3] = lrelu(v[3]);
        writeCf(acts, rw + mt * 16 + qd * 4, 32 + mcol, v, zero4);
    }
    x4f[0] = readAf(acts, rw, 32, lane);
    x4f[1] = readAf(acts, rw + 16, 32, lane);

    // ===== D =====
    f32x4 accD[4][2];
#pragma unroll
    for (int nt = 0; nt < 4; nt++) {
        float bv = ws[BD + nt * 16 + mcol];
        accD[nt][0] = (f32x4){bv, bv, bv, bv};
        accD[nt][1] = accD[nt][0];
    }
#pragma unroll
    for (int nt = 0; nt < 4; nt++)
        t2p(accD[nt][0], accD[nt][1], x4f[0], x4f[1],
            gfragH(wl, W_D + nt * 1024), gfragH(wl, W_D + nt * 1024 + 512));
#pragma unroll
    for (int mt = 0; mt < 2; mt++) {
        writeCf(acts, rw + mt * 16 + qd * 4, mcol,      accD[0][mt], accD[1][mt]);
        writeCf(acts, rw + mt * 16 + qd * 4, 16 + mcol, accD[2][mt], accD[3][mt]);
    }
    half8 xdf[2][2];
#pragma unroll
    for (int kt = 0; kt < 2; kt++)
#pragma unroll
        for (int mt = 0; mt < 2; mt++)
            xdf[kt][mt] = readAf(acts, rw + mt * 16, kt * 16, lane);

    // x6a init: b5 - x1, via MFMA of x1f against negated identity (C-layout)
    f32x4 x6a[4][2];
#pragma unroll
    for (int nt = 0; nt < 4; nt++) {
        float bv = ws[B5 + nt * 16 + mcol];
        half8 nI = gfragH(wl, W_NI + nt * 512);
#pragma unroll
        for (int mt = 0; mt < 2; mt++) {
            f32x4 v = {bv, bv, bv, bv};
            x6a[nt][mt] = MFMAH(x1f[nt >> 1][mt], nI, v);
        }
    }

    // ===== h4/h5 chunks: fully unrolled, double-buffered scratch slot =====
#pragma unroll
    for (int c = 0; c < 4; c++) {
        const int slot = 32 + (c & 1) * 16;
        f32x4 acc5[2][2];
#pragma unroll
        for (int nt2 = 0; nt2 < 2; nt2++) {
            float bv = ws[B4 + c * 32 + nt2 * 16 + mcol];
            acc5[nt2][0] = (f32x4){bv, bv, bv, bv};
            acc5[nt2][1] = acc5[nt2][0];
        }
#pragma unroll
        for (int nt2 = 0; nt2 < 2; nt2++)
#pragma unroll
            for (int kt = 0; kt < 2; kt++)
                t2s(acc5[nt2][0], acc5[nt2][1], xdf[kt][0], xdf[kt][1],
                    gfragH(wl, W_H4C0 + c * 4096 + (nt2 * 2 + kt) * 512));
#pragma unroll
        for (int mt = 0; mt < 2; mt++) {
            f32x4 v0 = acc5[0][mt], v1 = acc5[1][mt];
            v0[0] = tanh_fast(v0[0]); v0[1] = tanh_fast(v0[1]);
            v0[2] = tanh_fast(v0[2]); v0[3] = tanh_fast(v0[3]);
            v1[0] = tanh_fast(v1[0]); v1[1] = tanh_fast(v1[1]);
            v1[2] = tanh_fast(v1[2]); v1[3] = tanh_fast(v1[3]);
            writeCf(acts, rw + mt * 16 + qd * 4, slot + mcol, v0, v1);
        }
        half8 chf[2];
        chf[0] = readAf(acts, rw, slot, lane);
        chf[1] = readAf(acts, rw + 16, slot, lane);
#pragma unroll
        for (int nt = 0; nt < 4; nt++)
            t2s(x6a[nt][0], x6a[nt][1], chf[0], chf[1],
                gfragH(wl, W_H5C0 + c * 4096 + nt * 512));
    }

    // ===== out =====
#pragma unroll
    for (int mt = 0; mt < 2; mt++) {
        writeCf(acts, rw + mt * 16 + qd * 4, mcol,      x6a[0][mt], x6a[1][mt]);
        writeCf(acts, rw + mt * 16 + qd * 4, 16 + mcol, x6a[2][mt], x6a[3][mt]);
    }
    f32x4 accO[2];
    {
        float bv = ws[BOUT + mcol];
        accO[0] = (f32x4){bv, bv, bv, bv};
        accO[1] = accO[0];
    }
#pragma unroll
    for (int kt = 0; kt < 2; kt++) {
        half8 a0 = readAf(acts, rw, kt * 16, lane), a1 = readAf(acts, rw + 16, kt * 16, lane);
        t2s(accO[0], accO[1], a0, a1, gfragH(wl, W_OUT + kt * 512));
    }
    if (mcol < 3) {
#pragma unroll
        for (int mt = 0; mt < 2; mt++) {
#pragma unroll
            for (int r = 0; r < 4; r++) {
                int p = p0 + wv * 32 + mt * 16 + qd * 4 + r;
                out[(bb * 3 + mcol) * HW + p] = lrelu(accO[mt][r]);
            }
        }
    }
}

extern "C" void kernel_launch(void* const* d_in, const int* in_sizes, int n_in,
                              void* d_out, int out_size, void* d_ws, size_t ws_size,
                              hipStream_t stream)
{
    const float* xin = (const float*)d_in[0];
    float* ws = (float*)d_ws;

    setup_all<<<75, 256, 0, stream>>>(
        (const float*)d_in[1],  (const float*)d_in[2],   // input
        (const float*)d_in[3],  (const float*)d_in[4],   // h1
        (const float*)d_in[5],  (const float*)d_in[6],   // h2
        (const float*)d_in[7],  (const float*)d_in[8],   // h3
        (const float*)d_in[9],  (const float*)d_in[10],  // h4
        (const float*)d_in[11], (const float*)d_in[12],  // h5
        (const float*)d_in[13], (const float*)d_in[14],  // out
        (const float*)d_in[15], (const float*)d_in[16],  // e1
        (const float*)d_in[17], (const float*)d_in[18],  // e2
        (const float*)d_in[19], (const float*)d_in[20],  // e3
        (const float*)d_in[21], (const float*)d_in[22],  // f1
        (const float*)d_in[23], (const float*)d_in[24],  // f2
        (const float*)d_in[25], (const float*)d_in[26],  // f3
        (const float*)d_in[27], (const float*)d_in[28],  // d1
        (const float*)d_in[29], (const float*)d_in[30],  // d2
        (const float*)d_in[31], (const float*)d_in[32],  // d3
        ws);

    fused_mfma<<<NBLK, 256, 0, stream>>>(xin, ws, (float*)d_out);
}